// Round 1
// baseline (468.707 us; speedup 1.0000x reference)
//
#include <hip/hip_runtime.h>

#define B_   8
#define TGT_ 256
#define SRC_ 512
#define D_   1024
#define H_   16
#define DH_  64

// ---------------------------------------------------------------------------
// Kernel 1: C[M,N] = relu(A[M,K] @ W[N,K]^T + bias[N])   (fp32, tiled)
// BM=BN=64, BK=16, 256 threads, 4x4 microtile per thread.
// LDS tiles stored transposed (k-major) so fragment loads are ds_read_b128.
// ---------------------------------------------------------------------------
#define BM 64
#define BN 64
#define BK 16

__global__ __launch_bounds__(256) void proj_relu_kernel(
    const float* __restrict__ A, const float* __restrict__ W,
    const float* __restrict__ bias, float* __restrict__ C,
    int M, int N, int K)
{
    __shared__ float As[BK][BM + 4];   // [k][m]
    __shared__ float Ws[BK][BN + 4];   // [k][n]

    const int tid = threadIdx.x;
    const int bm0 = blockIdx.x * BM;
    const int bn0 = blockIdx.y * BN;

    const int lr = tid >> 2;           // 0..63  (row within tile for loading)
    const int lc = (tid & 3) << 2;     // 0,4,8,12 (k offset for loading)
    const int tr = tid >> 4;           // 0..15 (micro row group)
    const int tc = tid & 15;           // 0..15 (micro col group)

    const float* Aptr = A + (size_t)(bm0 + lr) * K + lc;
    const float* Wptr = W + (size_t)(bn0 + lr) * K + lc;

    float acc[4][4];
#pragma unroll
    for (int i = 0; i < 4; ++i)
#pragma unroll
        for (int j = 0; j < 4; ++j) acc[i][j] = 0.0f;

    for (int k0 = 0; k0 < K; k0 += BK) {
        float4 av = *(const float4*)(Aptr + k0);
        float4 wv = *(const float4*)(Wptr + k0);
        __syncthreads();
        As[lc + 0][lr] = av.x; As[lc + 1][lr] = av.y;
        As[lc + 2][lr] = av.z; As[lc + 3][lr] = av.w;
        Ws[lc + 0][lr] = wv.x; Ws[lc + 1][lr] = wv.y;
        Ws[lc + 2][lr] = wv.z; Ws[lc + 3][lr] = wv.w;
        __syncthreads();
#pragma unroll
        for (int kk = 0; kk < BK; ++kk) {
            float4 af = *(const float4*)&As[kk][tr << 2];
            float4 wf = *(const float4*)&Ws[kk][tc << 2];
            float a4[4] = {af.x, af.y, af.z, af.w};
            float w4[4] = {wf.x, wf.y, wf.z, wf.w};
#pragma unroll
            for (int i = 0; i < 4; ++i)
#pragma unroll
                for (int j = 0; j < 4; ++j)
                    acc[i][j] = fmaf(a4[i], w4[j], acc[i][j]);
        }
    }

    float4 bv = *(const float4*)&bias[bn0 + (tc << 2)];
    const float b4[4] = {bv.x, bv.y, bv.z, bv.w};
#pragma unroll
    for (int i = 0; i < 4; ++i) {
        float4 o;
        o.x = fmaxf(acc[i][0] + b4[0], 0.0f);
        o.y = fmaxf(acc[i][1] + b4[1], 0.0f);
        o.z = fmaxf(acc[i][2] + b4[2], 0.0f);
        o.w = fmaxf(acc[i][3] + b4[3], 0.0f);
        *(float4*)&C[(size_t)(bm0 + (tr << 2) + i) * N + bn0 + (tc << 2)] = o;
    }
}

// ---------------------------------------------------------------------------
// Kernel 2: p[b,h,t,s] = sigmoid(((Q[b,t,h*64:]·K[b,s,h*64:]) * dh^-0.5 + eb) / T)
// Block: 256 threads -> 16 t x 64 s tile for one (b,h).
// LDS K tile stored k4-major: Kt[k4][s] (float4) -> conflict-free b128 reads.
// ---------------------------------------------------------------------------
__global__ __launch_bounds__(256) void energy_kernel(
    const float* __restrict__ Q, const float* __restrict__ K,
    const float* __restrict__ eb_ptr, float* __restrict__ P)
{
    __shared__ float4 Kt[DH_ / 4][64 + 1];  // [k4][s]
    __shared__ float4 Qt[DH_ / 4][16 + 1];  // [k4][t]

    const int tid = threadIdx.x;
    const int bh  = blockIdx.x;          // 0..127
    const int b   = bh >> 4;
    const int h   = bh & 15;
    const int t0  = blockIdx.y << 4;     // 16 targets / block
    const int s0  = blockIdx.z << 6;     // 64 sources / block

    const int r  = tid >> 4;             // 0..15
    const int c4 = (tid & 15) << 2;      // 0..60 step 4

    // Q tile: 16 rows x 64 cols
    {
        const float* src = Q + ((size_t)b * TGT_ + (t0 + r)) * D_ + h * DH_ + c4;
        Qt[c4 >> 2][r] = *(const float4*)src;
    }
    // K tile: 64 rows x 64 cols
#pragma unroll
    for (int u = 0; u < 4; ++u) {
        const int rr = (u << 4) + r;
        const float* src = K + ((size_t)b * SRC_ + (s0 + rr)) * D_ + h * DH_ + c4;
        Kt[c4 >> 2][rr] = *(const float4*)src;
    }
    __syncthreads();

    const int s  = tid & 63;
    const int tg = tid >> 6;             // 0..3 (wave id)
    float acc[4] = {0.f, 0.f, 0.f, 0.f};
#pragma unroll
    for (int k4 = 0; k4 < DH_ / 4; ++k4) {
        float4 kv = Kt[k4][s];
#pragma unroll
        for (int i = 0; i < 4; ++i) {
            float4 qv = Qt[k4][(tg << 2) + i];
            acc[i] = fmaf(qv.x, kv.x, acc[i]);
            acc[i] = fmaf(qv.y, kv.y, acc[i]);
            acc[i] = fmaf(qv.z, kv.z, acc[i]);
            acc[i] = fmaf(qv.w, kv.w, acc[i]);
        }
    }
    const float eb = eb_ptr[0];
#pragma unroll
    for (int i = 0; i < 4; ++i) {
        float x = (acc[i] * 0.125f + eb) * 5.0f;   // (e*dh^-0.5 + eb)/0.2
        float p = 1.0f / (1.0f + __expf(-x));
        P[((size_t)bh * TGT_ + (t0 + (tg << 2) + i)) * SRC_ + s0 + s] = p;
    }
}

// ---------------------------------------------------------------------------
// Kernel 3: monotonic alignment.
//   c_i[n] = alpha_{i-1}[n] + (1 - p_i[n-1]) * c_i[n-1];  alpha_i = p_i * c_i
// One wave (64 lanes) per bh; 8 contiguous n per lane, alpha in registers.
// Division-free (a,b)-operator scan: shfl Hillis-Steele, no LDS, no barriers.
// ---------------------------------------------------------------------------
__global__ __launch_bounds__(64) void align_kernel(
    const float* __restrict__ P, float* __restrict__ Alpha)
{
    const int bh   = blockIdx.x;
    const int lane = threadIdx.x;
    const float* prow = P + (size_t)bh * TGT_ * SRC_;
    float* arow       = Alpha + (size_t)bh * TGT_ * SRC_;
    const int n0 = lane << 3;           // 8 elements per lane

    float bprev[8];
#pragma unroll
    for (int j = 0; j < 8; ++j) bprev[j] = 0.0f;
    if (lane == 0) bprev[0] = 1.0f;     // alpha_{-1} = delta_0

    float4 c0 = *(const float4*)&prow[n0];
    float4 c1 = *(const float4*)&prow[n0 + 4];

    for (int i = 0; i < TGT_; ++i) {
        float pl[8] = {c0.x, c0.y, c0.z, c0.w, c1.x, c1.y, c1.z, c1.w};
        if (i + 1 < TGT_) {             // prefetch next row
            const float* nxt = prow + (size_t)(i + 1) * SRC_ + n0;
            c0 = *(const float4*)nxt;
            c1 = *(const float4*)(nxt + 4);
        }

        // a[n] = 1 - p_i[n-1]; a[0] := 0 (c[-1] unused)
        float pm1 = __shfl_up(pl[7], 1, 64);   // prev lane's last p
        float a[8];
        a[0] = (lane == 0) ? 0.0f : (1.0f - pm1);
#pragma unroll
        for (int j = 1; j < 8; ++j) a[j] = 1.0f - pl[j - 1];

        // local inclusive composition within lane: op = (A, B), c -> A*c + B
        float Aj[8], Bj[8];
        float A = a[0], Bv = bprev[0];
        Aj[0] = A; Bj[0] = Bv;
#pragma unroll
        for (int j = 1; j < 8; ++j) {
            Bv = fmaf(a[j], Bv, bprev[j]);
            A  = a[j] * A;
            Aj[j] = A; Bj[j] = Bv;
        }

        // wave-level inclusive scan of per-lane totals (A, Bv)
        float As_ = A, Bs = Bv;
#pragma unroll
        for (int off = 1; off < 64; off <<= 1) {
            float Au = __shfl_up(As_, off, 64);
            float Bu = __shfl_up(Bs, off, 64);
            if (lane >= off) {
                Bs  = fmaf(As_, Bu, Bs);
                As_ = As_ * Au;
            }
        }
        float cin = __shfl_up(Bs, 1, 64);
        if (lane == 0) cin = 0.0f;

        float an[8];
#pragma unroll
        for (int j = 0; j < 8; ++j) {
            float c = fmaf(Aj[j], cin, Bj[j]);
            an[j] = pl[j] * c;
            bprev[j] = an[j];
        }
        float4 o0 = {an[0], an[1], an[2], an[3]};
        float4 o1 = {an[4], an[5], an[6], an[7]};
        float* dst = arow + (size_t)i * SRC_ + n0;
        *(float4*)dst       = o0;
        *(float4*)(dst + 4) = o1;
    }
}

// ---------------------------------------------------------------------------
extern "C" void kernel_launch(void* const* d_in, const int* in_sizes, int n_in,
                              void* d_out, int out_size, void* d_ws, size_t ws_size,
                              hipStream_t stream) {
    const float* seqs = (const float*)d_in[0];   // (8,256,1024)
    const float* keys = (const float*)d_in[1];   // (8,512,1024)
    const float* q_w  = (const float*)d_in[2];   // (1024,1024)
    const float* q_b  = (const float*)d_in[3];   // (1024,)
    const float* k_w  = (const float*)d_in[4];   // (1024,1024)
    const float* k_b  = (const float*)d_in[5];   // (1024,)
    const float* eb   = (const float*)d_in[6];   // (1,)

    float* out   = (float*)d_out;
    float* P     = out;                                          // (8,16,256,512)
    float* Alpha = out + (size_t)B_ * H_ * TGT_ * SRC_;          // (8,16,256,512)

    float* Qws = (float*)d_ws;                                   // 2048x1024 f32
    float* Kws = Qws + (size_t)B_ * TGT_ * D_;                   // 4096x1024 f32

    // Projections
    {
        dim3 grid(B_ * TGT_ / BM, D_ / BN);
        proj_relu_kernel<<<grid, 256, 0, stream>>>(seqs, q_w, q_b, Qws,
                                                   B_ * TGT_, D_, D_);
    }
    {
        dim3 grid(B_ * SRC_ / BM, D_ / BN);
        proj_relu_kernel<<<grid, 256, 0, stream>>>(keys, k_w, k_b, Kws,
                                                   B_ * SRC_, D_, D_);
    }
    // Energy + sigmoid -> p_choose
    {
        dim3 grid(B_ * H_, TGT_ / 16, SRC_ / 64);
        energy_kernel<<<grid, 256, 0, stream>>>(Qws, Kws, eb, P);
    }
    // Monotonic alignment -> alpha
    {
        align_kernel<<<dim3(B_ * H_), 64, 0, stream>>>(P, Alpha);
    }
}

// Round 2
// 350.756 us; speedup vs baseline: 1.3363x; 1.3363x over previous
//
#include <hip/hip_runtime.h>

#define B_   8
#define TGT_ 256
#define SRC_ 512
#define D_   1024
#define H_   16
#define DH_  64

typedef _Float16 half4 __attribute__((ext_vector_type(4)));
typedef _Float16 half8 __attribute__((ext_vector_type(8)));
typedef float    floatx4 __attribute__((ext_vector_type(4)));

__device__ __forceinline__ void async_ld16(const void* g, void* l) {
    __builtin_amdgcn_global_load_lds(
        (const __attribute__((address_space(1))) void*)g,
        (__attribute__((address_space(3))) void*)l, 16, 0, 0);
}

// ---------------------------------------------------------------------------
// Kernel 0: fp32 -> f16 conversion for seqs / keys / q_w / k_w.
// 1024 elements per block (256 thr x float4). Block ranges hardcoded.
// ---------------------------------------------------------------------------
__global__ __launch_bounds__(256) void cvt_kernel(
    const float* __restrict__ s0, const float* __restrict__ s1,
    const float* __restrict__ s2, const float* __restrict__ s3,
    _Float16* __restrict__ d0, _Float16* __restrict__ d1,
    _Float16* __restrict__ d2, _Float16* __restrict__ d3)
{
    const int bid = blockIdx.x;
    const float* src; _Float16* dst; int base;
    if      (bid < 2048) { src = s0; dst = d0; base = bid;        }  // seqs 2M
    else if (bid < 6144) { src = s1; dst = d1; base = bid - 2048; }  // keys 4M
    else if (bid < 7168) { src = s2; dst = d2; base = bid - 6144; }  // q_w 1M
    else                 { src = s3; dst = d3; base = bid - 7168; }  // k_w 1M
    const int idx = (base * 256 + threadIdx.x) * 4;
    float4 v = *(const float4*)(src + idx);
    half4 o = { (_Float16)v.x, (_Float16)v.y, (_Float16)v.z, (_Float16)v.w };
    *(half4*)(dst + idx) = o;
}

// ---------------------------------------------------------------------------
// Kernel 1: C[M,N] = f16(relu(A[M,K] @ W[N,K]^T + bias[N]))  via MFMA f16.
// BM=128 BN=64 BK=32, 256 threads, 2x2 waves, each wave 64x32 (4x2 MFMA tiles).
// Staging via global_load_lds width=16 (wave-uniform base + lane*16 layout).
// ---------------------------------------------------------------------------
__global__ __launch_bounds__(256) void proj_mfma_kernel(
    const _Float16* __restrict__ A, const _Float16* __restrict__ W,
    const float* __restrict__ bias, _Float16* __restrict__ C,
    int M, int N, int K)
{
    __shared__ _Float16 As[128 * 32];   // [row][k], row stride 32 elem = 64 B
    __shared__ _Float16 Ws[64 * 32];

    const int tid  = threadIdx.x;
    const int bm0  = blockIdx.x * 128;
    const int bn0  = blockIdx.y * 64;
    const int lane = tid & 63;
    const int wid  = tid >> 6;
    const int wm   = (wid >> 1) * 64;   // 0 / 64
    const int wn   = (wid & 1) * 32;    // 0 / 32

    // staging addresses: chunk c covers row c>>2, k-bytes (c&3)*16
    const int c1 = tid + 256;
    const _Float16* gA0 = A + (size_t)(bm0 + (tid >> 2)) * K + (tid & 3) * 8;
    const _Float16* gA1 = A + (size_t)(bm0 + (c1  >> 2)) * K + (c1  & 3) * 8;
    const _Float16* gW  = W + (size_t)(bn0 + (tid >> 2)) * K + (tid & 3) * 8;
    _Float16* lA0 = As + tid * 8;
    _Float16* lA1 = As + c1 * 8;
    _Float16* lW  = Ws + tid * 8;

    floatx4 acc[4][2];
#pragma unroll
    for (int i = 0; i < 4; ++i)
#pragma unroll
        for (int j = 0; j < 2; ++j) acc[i][j] = (floatx4){0.f, 0.f, 0.f, 0.f};

    const int fm = lane & 15;            // frag row/col within 16
    const int fk = (lane >> 4) * 8;      // frag k offset
    const _Float16* aF = As + (wm + fm) * 32 + fk;
    const _Float16* bF = Ws + (wn + fm) * 32 + fk;

    for (int k0 = 0; k0 < K; k0 += 32) {
        __syncthreads();
        async_ld16(gA0 + k0, lA0);
        async_ld16(gA1 + k0, lA1);
        async_ld16(gW  + k0, lW);
        __syncthreads();   // drains vmcnt before barrier

        half8 a0 = *(const half8*)(aF);
        half8 a1 = *(const half8*)(aF + 16 * 32);
        half8 a2 = *(const half8*)(aF + 32 * 32);
        half8 a3 = *(const half8*)(aF + 48 * 32);
        half8 b0 = *(const half8*)(bF);
        half8 b1 = *(const half8*)(bF + 16 * 32);

        acc[0][0] = __builtin_amdgcn_mfma_f32_16x16x32_f16(a0, b0, acc[0][0], 0, 0, 0);
        acc[1][0] = __builtin_amdgcn_mfma_f32_16x16x32_f16(a1, b0, acc[1][0], 0, 0, 0);
        acc[2][0] = __builtin_amdgcn_mfma_f32_16x16x32_f16(a2, b0, acc[2][0], 0, 0, 0);
        acc[3][0] = __builtin_amdgcn_mfma_f32_16x16x32_f16(a3, b0, acc[3][0], 0, 0, 0);
        acc[0][1] = __builtin_amdgcn_mfma_f32_16x16x32_f16(a0, b1, acc[0][1], 0, 0, 0);
        acc[1][1] = __builtin_amdgcn_mfma_f32_16x16x32_f16(a1, b1, acc[1][1], 0, 0, 0);
        acc[2][1] = __builtin_amdgcn_mfma_f32_16x16x32_f16(a2, b1, acc[2][1], 0, 0, 0);
        acc[3][1] = __builtin_amdgcn_mfma_f32_16x16x32_f16(a3, b1, acc[3][1], 0, 0, 0);
    }

    // epilogue: C/D layout col=lane&15, row=(lane>>4)*4+reg
    const int er = (lane >> 4) * 4;
#pragma unroll
    for (int nt = 0; nt < 2; ++nt) {
        const int col = bn0 + wn + nt * 16 + fm;
        const float bv = bias[col];
#pragma unroll
        for (int mt = 0; mt < 4; ++mt) {
            const int row0 = bm0 + wm + mt * 16 + er;
#pragma unroll
            for (int r = 0; r < 4; ++r) {
                float v = acc[mt][nt][r] + bv;
                v = fmaxf(v, 0.0f);
                C[(size_t)(row0 + r) * N + col] = (_Float16)v;
            }
        }
    }
}

// ---------------------------------------------------------------------------
// Kernel 2: p = sigmoid(((Q·K)/8 + eb)/0.2), f16 Q/K inputs, 32t x 64s tiles.
// ---------------------------------------------------------------------------
__global__ __launch_bounds__(256) void energy_kernel(
    const _Float16* __restrict__ Q, const _Float16* __restrict__ K,
    const float* __restrict__ eb_ptr, float* __restrict__ P)
{
    __shared__ float4 Kt[DH_ / 4][64];   // [k4][s]
    __shared__ float4 Qt[DH_ / 4][32];   // [k4][t]

    const int tid = threadIdx.x;
    const int bh  = blockIdx.x;          // 0..127
    const int b   = bh >> 4;
    const int h   = bh & 15;
    const int t0  = blockIdx.y << 5;     // 32 targets
    const int s0  = blockIdx.z << 6;     // 64 sources

    // Q tile 32x64: one half8 per thread
    {
        const int qr = tid >> 3, qc = (tid & 7) * 8;
        half8 hv = *(const half8*)(Q + ((size_t)b * TGT_ + t0 + qr) * D_ + h * DH_ + qc);
        float4 lo = {(float)hv[0], (float)hv[1], (float)hv[2], (float)hv[3]};
        float4 hi = {(float)hv[4], (float)hv[5], (float)hv[6], (float)hv[7]};
        Qt[(qc >> 2) + 0][qr] = lo;
        Qt[(qc >> 2) + 1][qr] = hi;
    }
    // K tile 64x64: two half8 per thread
#pragma unroll
    for (int u = 0; u < 2; ++u) {
        const int kr = (tid >> 3) + u * 32, kc = (tid & 7) * 8;
        half8 hv = *(const half8*)(K + ((size_t)b * SRC_ + s0 + kr) * D_ + h * DH_ + kc);
        float4 lo = {(float)hv[0], (float)hv[1], (float)hv[2], (float)hv[3]};
        float4 hi = {(float)hv[4], (float)hv[5], (float)hv[6], (float)hv[7]};
        Kt[(kc >> 2) + 0][kr] = lo;
        Kt[(kc >> 2) + 1][kr] = hi;
    }
    __syncthreads();

    const int s  = tid & 63;
    const int tg = tid >> 6;             // wave id: t rows tg*8..tg*8+7
    float acc[8] = {0.f, 0.f, 0.f, 0.f, 0.f, 0.f, 0.f, 0.f};
#pragma unroll
    for (int k4 = 0; k4 < DH_ / 4; ++k4) {
        float4 kv = Kt[k4][s];
#pragma unroll
        for (int i = 0; i < 8; ++i) {
            float4 qv = Qt[k4][tg * 8 + i];
            acc[i] = fmaf(qv.x, kv.x, acc[i]);
            acc[i] = fmaf(qv.y, kv.y, acc[i]);
            acc[i] = fmaf(qv.z, kv.z, acc[i]);
            acc[i] = fmaf(qv.w, kv.w, acc[i]);
        }
    }
    const float eb = eb_ptr[0];
#pragma unroll
    for (int i = 0; i < 8; ++i) {
        float x = (acc[i] * 0.125f + eb) * 5.0f;
        float p = 1.0f / (1.0f + __expf(-x));
        P[((size_t)bh * TGT_ + (t0 + tg * 8 + i)) * SRC_ + s0 + s] = p;
    }
}

// ---------------------------------------------------------------------------
// Kernel 3: monotonic alignment (unchanged, fp32).
//   c_i[n] = alpha_{i-1}[n] + (1 - p_i[n-1]) * c_i[n-1];  alpha_i = p_i * c_i
// One wave per bh; division-free (A,B)-operator shfl scan.
// ---------------------------------------------------------------------------
__global__ __launch_bounds__(64) void align_kernel(
    const float* __restrict__ P, float* __restrict__ Alpha)
{
    const int bh   = blockIdx.x;
    const int lane = threadIdx.x;
    const float* prow = P + (size_t)bh * TGT_ * SRC_;
    float* arow       = Alpha + (size_t)bh * TGT_ * SRC_;
    const int n0 = lane << 3;

    float bprev[8];
#pragma unroll
    for (int j = 0; j < 8; ++j) bprev[j] = 0.0f;
    if (lane == 0) bprev[0] = 1.0f;

    float4 c0 = *(const float4*)&prow[n0];
    float4 c1 = *(const float4*)&prow[n0 + 4];

    for (int i = 0; i < TGT_; ++i) {
        float pl[8] = {c0.x, c0.y, c0.z, c0.w, c1.x, c1.y, c1.z, c1.w};
        if (i + 1 < TGT_) {
            const float* nxt = prow + (size_t)(i + 1) * SRC_ + n0;
            c0 = *(const float4*)nxt;
            c1 = *(const float4*)(nxt + 4);
        }

        float pm1 = __shfl_up(pl[7], 1, 64);
        float a[8];
        a[0] = (lane == 0) ? 0.0f : (1.0f - pm1);
#pragma unroll
        for (int j = 1; j < 8; ++j) a[j] = 1.0f - pl[j - 1];

        float Aj[8], Bj[8];
        float A = a[0], Bv = bprev[0];
        Aj[0] = A; Bj[0] = Bv;
#pragma unroll
        for (int j = 1; j < 8; ++j) {
            Bv = fmaf(a[j], Bv, bprev[j]);
            A  = a[j] * A;
            Aj[j] = A; Bj[j] = Bv;
        }

        float As_ = A, Bs = Bv;
#pragma unroll
        for (int off = 1; off < 64; off <<= 1) {
            float Au = __shfl_up(As_, off, 64);
            float Bu = __shfl_up(Bs, off, 64);
            if (lane >= off) {
                Bs  = fmaf(As_, Bu, Bs);
                As_ = As_ * Au;
            }
        }
        float cin = __shfl_up(Bs, 1, 64);
        if (lane == 0) cin = 0.0f;

        float an[8];
#pragma unroll
        for (int j = 0; j < 8; ++j) {
            float c = fmaf(Aj[j], cin, Bj[j]);
            an[j] = pl[j] * c;
            bprev[j] = an[j];
        }
        float4 o0 = {an[0], an[1], an[2], an[3]};
        float4 o1 = {an[4], an[5], an[6], an[7]};
        float* dst = arow + (size_t)i * SRC_ + n0;
        *(float4*)dst       = o0;
        *(float4*)(dst + 4) = o1;
    }
}

// ---------------------------------------------------------------------------
extern "C" void kernel_launch(void* const* d_in, const int* in_sizes, int n_in,
                              void* d_out, int out_size, void* d_ws, size_t ws_size,
                              hipStream_t stream) {
    const float* seqs = (const float*)d_in[0];
    const float* keys = (const float*)d_in[1];
    const float* q_w  = (const float*)d_in[2];
    const float* q_b  = (const float*)d_in[3];
    const float* k_w  = (const float*)d_in[4];
    const float* k_b  = (const float*)d_in[5];
    const float* eb   = (const float*)d_in[6];

    float* out   = (float*)d_out;
    float* P     = out;                                   // (8,16,256,512)
    float* Alpha = out + (size_t)B_ * H_ * TGT_ * SRC_;   // (8,16,256,512)

    // f16 workspace: Qh/Kh in d_ws (12 MB); input staging carved from the
    // Alpha half of d_out (written only later, by align_kernel).
    _Float16* Qh = (_Float16*)d_ws;                       // 2048x1024
    _Float16* Kh = Qh + (size_t)B_ * TGT_ * D_;           // 4096x1024
    _Float16* seqs_h = (_Float16*)Alpha;                  // 2M halves
    _Float16* keys_h = seqs_h + (size_t)B_ * TGT_ * D_;   // 4M
    _Float16* qw_h   = keys_h + (size_t)B_ * SRC_ * D_;   // 1M
    _Float16* kw_h   = qw_h + (size_t)D_ * D_;            // 1M

    cvt_kernel<<<dim3(8192), 256, 0, stream>>>(seqs, keys, q_w, k_w,
                                               seqs_h, keys_h, qw_h, kw_h);
    {
        dim3 grid(B_ * TGT_ / 128, D_ / 64);
        proj_mfma_kernel<<<grid, 256, 0, stream>>>(seqs_h, qw_h, q_b, Qh,
                                                   B_ * TGT_, D_, D_);
    }
    {
        dim3 grid(B_ * SRC_ / 128, D_ / 64);
        proj_mfma_kernel<<<grid, 256, 0, stream>>>(keys_h, kw_h, k_b, Kh,
                                                   B_ * SRC_, D_, D_);
    }
    {
        dim3 grid(B_ * H_, TGT_ / 32, SRC_ / 64);
        energy_kernel<<<grid, 256, 0, stream>>>(Qh, Kh, eb, P);
    }
    align_kernel<<<dim3(B_ * H_), 64, 0, stream>>>(P, Alpha);
}

// Round 3
// 311.392 us; speedup vs baseline: 1.5052x; 1.1264x over previous
//
#include <hip/hip_runtime.h>

#define B_   8
#define TGT_ 256
#define SRC_ 512
#define D_   1024
#define H_   16
#define DH_  64

typedef _Float16 half4 __attribute__((ext_vector_type(4)));
typedef _Float16 half8 __attribute__((ext_vector_type(8)));
typedef float    floatx4 __attribute__((ext_vector_type(4)));

__device__ __forceinline__ void async_ld16(const void* g, void* l) {
    __builtin_amdgcn_global_load_lds(
        (const __attribute__((address_space(1))) void*)g,
        (__attribute__((address_space(3))) void*)l, 16, 0, 0);
}

// DPP move: bound_ctrl=1 -> out-of-range source lanes produce 0.0f
template <int CTRL>
__device__ __forceinline__ float dppf(float x) {
    return __int_as_float(__builtin_amdgcn_update_dpp(
        0, __float_as_int(x), CTRL, 0xF, 0xF, true));
}
__device__ __forceinline__ float rdlane(float x, int lane) {
    return __int_as_float(__builtin_amdgcn_readlane(__float_as_int(x), lane));
}

// ---------------------------------------------------------------------------
// Kernel 0: fp32 -> f16 conversion for seqs / keys / q_w / k_w.
// ---------------------------------------------------------------------------
__global__ __launch_bounds__(256) void cvt_kernel(
    const float* __restrict__ s0, const float* __restrict__ s1,
    const float* __restrict__ s2, const float* __restrict__ s3,
    _Float16* __restrict__ d0, _Float16* __restrict__ d1,
    _Float16* __restrict__ d2, _Float16* __restrict__ d3)
{
    const int bid = blockIdx.x;
    const float* src; _Float16* dst; int base;
    if      (bid < 2048) { src = s0; dst = d0; base = bid;        }
    else if (bid < 6144) { src = s1; dst = d1; base = bid - 2048; }
    else if (bid < 7168) { src = s2; dst = d2; base = bid - 6144; }
    else                 { src = s3; dst = d3; base = bid - 7168; }
    const int idx = (base * 256 + threadIdx.x) * 4;
    float4 v = *(const float4*)(src + idx);
    half4 o = { (_Float16)v.x, (_Float16)v.y, (_Float16)v.z, (_Float16)v.w };
    *(half4*)(dst + idx) = o;
}

// ---------------------------------------------------------------------------
// Kernel 1: C[M,N] = f16(relu(A[M,K] @ W[N,K]^T + bias[N]))  via MFMA f16.
// (unchanged from round 2 — validated)
// ---------------------------------------------------------------------------
__global__ __launch_bounds__(256) void proj_mfma_kernel(
    const _Float16* __restrict__ A, const _Float16* __restrict__ W,
    const float* __restrict__ bias, _Float16* __restrict__ C,
    int M, int N, int K)
{
    __shared__ _Float16 As[128 * 32];
    __shared__ _Float16 Ws[64 * 32];

    const int tid  = threadIdx.x;
    const int bm0  = blockIdx.x * 128;
    const int bn0  = blockIdx.y * 64;
    const int lane = tid & 63;
    const int wid  = tid >> 6;
    const int wm   = (wid >> 1) * 64;
    const int wn   = (wid & 1) * 32;

    const int c1 = tid + 256;
    const _Float16* gA0 = A + (size_t)(bm0 + (tid >> 2)) * K + (tid & 3) * 8;
    const _Float16* gA1 = A + (size_t)(bm0 + (c1  >> 2)) * K + (c1  & 3) * 8;
    const _Float16* gW  = W + (size_t)(bn0 + (tid >> 2)) * K + (tid & 3) * 8;
    _Float16* lA0 = As + tid * 8;
    _Float16* lA1 = As + c1 * 8;
    _Float16* lW  = Ws + tid * 8;

    floatx4 acc[4][2];
#pragma unroll
    for (int i = 0; i < 4; ++i)
#pragma unroll
        for (int j = 0; j < 2; ++j) acc[i][j] = (floatx4){0.f, 0.f, 0.f, 0.f};

    const int fm = lane & 15;
    const int fk = (lane >> 4) * 8;
    const _Float16* aF = As + (wm + fm) * 32 + fk;
    const _Float16* bF = Ws + (wn + fm) * 32 + fk;

    for (int k0 = 0; k0 < K; k0 += 32) {
        __syncthreads();
        async_ld16(gA0 + k0, lA0);
        async_ld16(gA1 + k0, lA1);
        async_ld16(gW  + k0, lW);
        __syncthreads();

        half8 a0 = *(const half8*)(aF);
        half8 a1 = *(const half8*)(aF + 16 * 32);
        half8 a2 = *(const half8*)(aF + 32 * 32);
        half8 a3 = *(const half8*)(aF + 48 * 32);
        half8 b0 = *(const half8*)(bF);
        half8 b1 = *(const half8*)(bF + 16 * 32);

        acc[0][0] = __builtin_amdgcn_mfma_f32_16x16x32_f16(a0, b0, acc[0][0], 0, 0, 0);
        acc[1][0] = __builtin_amdgcn_mfma_f32_16x16x32_f16(a1, b0, acc[1][0], 0, 0, 0);
        acc[2][0] = __builtin_amdgcn_mfma_f32_16x16x32_f16(a2, b0, acc[2][0], 0, 0, 0);
        acc[3][0] = __builtin_amdgcn_mfma_f32_16x16x32_f16(a3, b0, acc[3][0], 0, 0, 0);
        acc[0][1] = __builtin_amdgcn_mfma_f32_16x16x32_f16(a0, b1, acc[0][1], 0, 0, 0);
        acc[1][1] = __builtin_amdgcn_mfma_f32_16x16x32_f16(a1, b1, acc[1][1], 0, 0, 0);
        acc[2][1] = __builtin_amdgcn_mfma_f32_16x16x32_f16(a2, b1, acc[2][1], 0, 0, 0);
        acc[3][1] = __builtin_amdgcn_mfma_f32_16x16x32_f16(a3, b1, acc[3][1], 0, 0, 0);
    }

    const int er = (lane >> 4) * 4;
#pragma unroll
    for (int nt = 0; nt < 2; ++nt) {
        const int col = bn0 + wn + nt * 16 + fm;
        const float bv = bias[col];
#pragma unroll
        for (int mt = 0; mt < 4; ++mt) {
            const int row0 = bm0 + wm + mt * 16 + er;
#pragma unroll
            for (int r = 0; r < 4; ++r) {
                float v = acc[mt][nt][r] + bv;
                v = fmaxf(v, 0.0f);
                C[(size_t)(row0 + r) * N + col] = (_Float16)v;
            }
        }
    }
}

// ---------------------------------------------------------------------------
// Kernel 2: energy via MFMA f16.  E[t][s] = sum_k Q[t,k]*K[s,k], k=dh=64.
// Block: 256 thr = 2x2 waves over a 64t x 128s tile of one (b,h).
// LDS layout: [kchunk][row][32 halves] (64B row stride, 2-way = free).
// p = sigmoid((E/8 + eb)/0.2) stored fp32.
// ---------------------------------------------------------------------------
__global__ __launch_bounds__(256) void energy_mfma_kernel(
    const _Float16* __restrict__ Q, const _Float16* __restrict__ K,
    const float* __restrict__ eb_ptr, float* __restrict__ P)
{
    __shared__ __align__(16) _Float16 Qt[2 * 64 * 32];    // 8 KB
    __shared__ __align__(16) _Float16 Kt[2 * 128 * 32];   // 16 KB

    const int tid = threadIdx.x;
    const int bh  = blockIdx.x;
    const int b   = bh >> 4;
    const int h   = bh & 15;
    const int t0  = blockIdx.y << 6;     // 64 targets
    const int s0  = blockIdx.z << 7;     // 128 sources

    // stage Q tile: 512 half8 units, 2 per thread
#pragma unroll
    for (int u = 0; u < 2; ++u) {
        const int unit = tid + u * 256;
        const int row = unit >> 3, hc = unit & 7;
        half8 v = *(const half8*)(Q + ((size_t)(b * TGT_ + t0 + row)) * D_ + h * DH_ + hc * 8);
        *(half8*)(Qt + (hc >> 2) * (64 * 32) + row * 32 + (hc & 3) * 8) = v;
    }
    // stage K tile: 1024 half8 units, 4 per thread
#pragma unroll
    for (int u = 0; u < 4; ++u) {
        const int unit = tid + u * 256;
        const int row = unit >> 3, hc = unit & 7;
        half8 v = *(const half8*)(K + ((size_t)(b * SRC_ + s0 + row)) * D_ + h * DH_ + hc * 8);
        *(half8*)(Kt + (hc >> 2) * (128 * 32) + row * 32 + (hc & 3) * 8) = v;
    }
    __syncthreads();

    const int lane = tid & 63;
    const int wid  = tid >> 6;
    const int wm   = (wid >> 1) * 32;    // t offset of wave
    const int wn   = (wid & 1) * 64;     // s offset of wave
    const int fm   = lane & 15;
    const int fk   = (lane >> 4) * 8;

    floatx4 acc[2][4];
#pragma unroll
    for (int i = 0; i < 2; ++i)
#pragma unroll
        for (int j = 0; j < 4; ++j) acc[i][j] = (floatx4){0.f, 0.f, 0.f, 0.f};

#pragma unroll
    for (int ks = 0; ks < 2; ++ks) {
        const _Float16* aB = Qt + ks * (64 * 32) + (wm + fm) * 32 + fk;
        const _Float16* bB = Kt + ks * (128 * 32) + (wn + fm) * 32 + fk;
        half8 a0 = *(const half8*)(aB);
        half8 a1 = *(const half8*)(aB + 16 * 32);
        half8 b0 = *(const half8*)(bB);
        half8 b1 = *(const half8*)(bB + 16 * 32);
        half8 b2 = *(const half8*)(bB + 32 * 32);
        half8 b3 = *(const half8*)(bB + 48 * 32);
        acc[0][0] = __builtin_amdgcn_mfma_f32_16x16x32_f16(a0, b0, acc[0][0], 0, 0, 0);
        acc[0][1] = __builtin_amdgcn_mfma_f32_16x16x32_f16(a0, b1, acc[0][1], 0, 0, 0);
        acc[0][2] = __builtin_amdgcn_mfma_f32_16x16x32_f16(a0, b2, acc[0][2], 0, 0, 0);
        acc[0][3] = __builtin_amdgcn_mfma_f32_16x16x32_f16(a0, b3, acc[0][3], 0, 0, 0);
        acc[1][0] = __builtin_amdgcn_mfma_f32_16x16x32_f16(a1, b0, acc[1][0], 0, 0, 0);
        acc[1][1] = __builtin_amdgcn_mfma_f32_16x16x32_f16(a1, b1, acc[1][1], 0, 0, 0);
        acc[1][2] = __builtin_amdgcn_mfma_f32_16x16x32_f16(a1, b2, acc[1][2], 0, 0, 0);
        acc[1][3] = __builtin_amdgcn_mfma_f32_16x16x32_f16(a1, b3, acc[1][3], 0, 0, 0);
    }

    const float eb = eb_ptr[0];
    const int er = (lane >> 4) * 4;
#pragma unroll
    for (int mt = 0; mt < 2; ++mt) {
#pragma unroll
        for (int nt = 0; nt < 4; ++nt) {
            const int s = s0 + wn + nt * 16 + fm;
#pragma unroll
            for (int r = 0; r < 4; ++r) {
                const int t = t0 + wm + mt * 16 + er + r;
                float x = (acc[mt][nt][r] * 0.125f + eb) * 5.0f;
                float p = 1.0f / (1.0f + __expf(-x));
                P[((size_t)bh * TGT_ + t) * SRC_ + s] = p;
            }
        }
    }
}

// ---------------------------------------------------------------------------
// Kernel 3: monotonic alignment, DPP-based scan (no ds_bpermute on the
// critical path).  c_i[n] = alpha_{i-1}[n] + (1-p_i[n-1])*c_i[n-1];
// alpha_i = p_i * c_i.  One wave per bh, 8 n per lane.
// Wave scan of per-lane operator totals (A,B):
//   - 16-lane-segment Kogge-Stone via DPP row_shr 1/2/4/8 (VALU latency)
//   - cross-segment prefix via v_readlane of lanes 15/31/47
//   - exclusive carry via DPP row_shr:1 of the inclusive + readlane patch
// ---------------------------------------------------------------------------
__global__ __launch_bounds__(64) void align_kernel(
    const float* __restrict__ P, float* __restrict__ Alpha)
{
    const int bh   = blockIdx.x;
    const int lane = threadIdx.x;
    const float* prow = P + (size_t)bh * TGT_ * SRC_;
    float* arow       = Alpha + (size_t)bh * TGT_ * SRC_;
    const int n0 = lane << 3;

    float bprev[8];
#pragma unroll
    for (int j = 0; j < 8; ++j) bprev[j] = 0.0f;
    if (lane == 0) bprev[0] = 1.0f;

    // 2-row-deep prefetch
    float4 c0a = *(const float4*)&prow[n0];
    float4 c0b = *(const float4*)&prow[n0 + 4];
    float4 c1a = *(const float4*)&prow[SRC_ + n0];
    float4 c1b = *(const float4*)&prow[SRC_ + n0 + 4];

    for (int i = 0; i < TGT_; ++i) {
        float pl[8] = {c0a.x, c0a.y, c0a.z, c0a.w, c1b.x, c0b.y, c0b.z, c0b.w};
        pl[4] = c0b.x;  // (keep initializer simple; fix slot 4)
        c0a = c1a; c0b = c1b;
        if (i + 2 < TGT_) {
            const float* nxt = prow + (size_t)(i + 2) * SRC_ + n0;
            c1a = *(const float4*)nxt;
            c1b = *(const float4*)(nxt + 4);
        }

        // pm1 = previous lane's pl[7] (wave-wide shift by 1)
        float pm1 = dppf<0x111>(pl[7]);                 // row_shr:1
        {
            float r15 = rdlane(pl[7], 15);
            float r31 = rdlane(pl[7], 31);
            float r47 = rdlane(pl[7], 47);
            pm1 = (lane == 16) ? r15 : pm1;
            pm1 = (lane == 32) ? r31 : pm1;
            pm1 = (lane == 48) ? r47 : pm1;
        }
        float a[8];
        a[0] = (lane == 0) ? 0.0f : (1.0f - pm1);
#pragma unroll
        for (int j = 1; j < 8; ++j) a[j] = 1.0f - pl[j - 1];

        // in-lane inclusive operator scan, seeded with bprev
        float Aj[8], Bj[8];
        float A = a[0], Bv = bprev[0];
        Aj[0] = A; Bj[0] = Bv;
#pragma unroll
        for (int j = 1; j < 8; ++j) {
            Bv = fmaf(a[j], Bv, bprev[j]);
            A  = a[j] * A;
            Aj[j] = A; Bj[j] = Bv;
        }

        // 16-lane-segment inclusive Kogge-Stone on (A,Bv) via DPP row_shr
        float As_ = A, Bs = Bv;
        {
            float Ash, Bsh;
            Ash = dppf<0x111>(As_); Bsh = dppf<0x111>(Bs);
            Ash = ((lane & 15) >= 1) ? Ash : 1.0f;
            Bs  = fmaf(As_, Bsh, Bs); As_ = As_ * Ash;
            Ash = dppf<0x112>(As_); Bsh = dppf<0x112>(Bs);
            Ash = ((lane & 15) >= 2) ? Ash : 1.0f;
            Bs  = fmaf(As_, Bsh, Bs); As_ = As_ * Ash;
            Ash = dppf<0x114>(As_); Bsh = dppf<0x114>(Bs);
            Ash = ((lane & 15) >= 4) ? Ash : 1.0f;
            Bs  = fmaf(As_, Bsh, Bs); As_ = As_ * Ash;
            Ash = dppf<0x118>(As_); Bsh = dppf<0x118>(Bs);
            Ash = ((lane & 15) >= 8) ? Ash : 1.0f;
            Bs  = fmaf(As_, Bsh, Bs); As_ = As_ * Ash;
        }

        // cross-segment prefix (B component only is needed downstream)
        float PB;
        {
            float A15 = rdlane(As_, 15), B15 = rdlane(Bs, 15);
            float A31 = rdlane(As_, 31), B31 = rdlane(Bs, 31);
            float B47 = rdlane(Bs, 47);
            float A47 = rdlane(As_, 47);
            float PB1 = B15;
            float PA1 = A15;
            float PB2 = fmaf(A31, PB1, B31);
            float PA2 = A31 * PA1;
            float PB3 = fmaf(A47, PB2, B47);
            (void)PA2; (void)A47;
            const int seg = lane >> 4;
            PB = (seg == 0) ? 0.0f : ((seg == 1) ? PB1 : ((seg == 2) ? PB2 : PB3));
        }

        // exclusive-in-segment from inclusive (shift by 1 within segment)
        float EA = dppf<0x111>(As_);
        float EB = dppf<0x111>(Bs);
        EA = (lane & 15) ? EA : 1.0f;     // segment-lane0 -> identity (1,0)
        float cin = fmaf(EA, PB, EB);     // carry into this lane

        float an[8];
#pragma unroll
        for (int j = 0; j < 8; ++j) {
            float c = fmaf(Aj[j], cin, Bj[j]);
            an[j] = pl[j] * c;
            bprev[j] = an[j];
        }
        float4 o0 = {an[0], an[1], an[2], an[3]};
        float4 o1 = {an[4], an[5], an[6], an[7]};
        float* dst = arow + (size_t)i * SRC_ + n0;
        *(float4*)dst       = o0;
        *(float4*)(dst + 4) = o1;
    }
}

// ---------------------------------------------------------------------------
extern "C" void kernel_launch(void* const* d_in, const int* in_sizes, int n_in,
                              void* d_out, int out_size, void* d_ws, size_t ws_size,
                              hipStream_t stream) {
    const float* seqs = (const float*)d_in[0];
    const float* keys = (const float*)d_in[1];
    const float* q_w  = (const float*)d_in[2];
    const float* q_b  = (const float*)d_in[3];
    const float* k_w  = (const float*)d_in[4];
    const float* k_b  = (const float*)d_in[5];
    const float* eb   = (const float*)d_in[6];

    float* out   = (float*)d_out;
    float* P     = out;
    float* Alpha = out + (size_t)B_ * H_ * TGT_ * SRC_;

    _Float16* Qh = (_Float16*)d_ws;
    _Float16* Kh = Qh + (size_t)B_ * TGT_ * D_;
    _Float16* seqs_h = (_Float16*)Alpha;
    _Float16* keys_h = seqs_h + (size_t)B_ * TGT_ * D_;
    _Float16* qw_h   = keys_h + (size_t)B_ * SRC_ * D_;
    _Float16* kw_h   = qw_h + (size_t)D_ * D_;

    cvt_kernel<<<dim3(8192), 256, 0, stream>>>(seqs, keys, q_w, k_w,
                                               seqs_h, keys_h, qw_h, kw_h);
    {
        dim3 grid(B_ * TGT_ / 128, D_ / 64);
        proj_mfma_kernel<<<grid, 256, 0, stream>>>(seqs_h, qw_h, q_b, Qh,
                                                   B_ * TGT_, D_, D_);
    }
    {
        dim3 grid(B_ * SRC_ / 128, D_ / 64);
        proj_mfma_kernel<<<grid, 256, 0, stream>>>(keys_h, kw_h, k_b, Kh,
                                                   B_ * SRC_, D_, D_);
    }
    {
        dim3 grid(B_ * H_, TGT_ / 64, SRC_ / 128);
        energy_mfma_kernel<<<grid, 256, 0, stream>>>(Qh, Kh, eb, P);
    }
    align_kernel<<<dim3(B_ * H_), 64, 0, stream>>>(P, Alpha);
}

// Round 4
// 281.764 us; speedup vs baseline: 1.6635x; 1.1051x over previous
//
#include <hip/hip_runtime.h>

#define B_   8
#define TGT_ 256
#define SRC_ 512
#define D_   1024
#define H_   16
#define DH_  64

typedef _Float16 half4 __attribute__((ext_vector_type(4)));
typedef _Float16 half8 __attribute__((ext_vector_type(8)));
typedef float    floatx4 __attribute__((ext_vector_type(4)));

// DPP move: bound_ctrl=1 -> out-of-range source lanes produce 0.0f
template <int CTRL>
__device__ __forceinline__ float dppf(float x) {
    return __int_as_float(__builtin_amdgcn_update_dpp(
        0, __float_as_int(x), CTRL, 0xF, 0xF, true));
}
__device__ __forceinline__ float rdlane(float x, int lane) {
    return __int_as_float(__builtin_amdgcn_readlane(__float_as_int(x), lane));
}

// ---------------------------------------------------------------------------
// Kernel 0: fp32 -> f16 conversion for seqs / keys / q_w / k_w.
// ---------------------------------------------------------------------------
__global__ __launch_bounds__(256) void cvt_kernel(
    const float* __restrict__ s0, const float* __restrict__ s1,
    const float* __restrict__ s2, const float* __restrict__ s3,
    _Float16* __restrict__ d0, _Float16* __restrict__ d1,
    _Float16* __restrict__ d2, _Float16* __restrict__ d3)
{
    const int bid = blockIdx.x;
    const float* src; _Float16* dst; int base;
    if      (bid < 2048) { src = s0; dst = d0; base = bid;        }
    else if (bid < 6144) { src = s1; dst = d1; base = bid - 2048; }
    else if (bid < 7168) { src = s2; dst = d2; base = bid - 6144; }
    else                 { src = s3; dst = d3; base = bid - 7168; }
    const int idx = (base * 256 + threadIdx.x) * 4;
    float4 v = *(const float4*)(src + idx);
    half4 o = { (_Float16)v.x, (_Float16)v.y, (_Float16)v.z, (_Float16)v.w };
    *(half4*)(dst + idx) = o;
}

// ---------------------------------------------------------------------------
// Kernel 1: C[M,N] = f16(relu(A[M,K] @ W[N,K]^T + bias[N]))  via MFMA f16.
// LDS-FREE: each lane loads its 16x16x32 fragments (8 contiguous k halves =
// 16 B) straight from global. No barriers in the K-loop -> loads pipeline
// with fine-grained vmcnt instead of a per-iteration vmcnt(0) barrier drain.
// Block = 256 thr = 2x2 waves over a 128m x 64n tile; wave = 64m x 32n.
// ---------------------------------------------------------------------------
__global__ __launch_bounds__(256) void proj_mfma_kernel(
    const _Float16* __restrict__ A, const _Float16* __restrict__ W,
    const float* __restrict__ bias, _Float16* __restrict__ C,
    int M, int N, int K)
{
    const int tid  = threadIdx.x;
    const int lane = tid & 63;
    const int wid  = tid >> 6;
    const int bm0  = blockIdx.x * 128;
    const int bn0  = blockIdx.y * 64;
    const int wm   = (wid >> 1) * 64;
    const int wn   = (wid & 1) * 32;
    const int fm   = lane & 15;
    const int fk   = (lane >> 4) * 8;

    const _Float16* aR = A + (size_t)(bm0 + wm + fm) * K + fk;
    const _Float16* bR = W + (size_t)(bn0 + wn + fm) * K + fk;
    const size_t rs16 = (size_t)16 * K;

    floatx4 acc[4][2];
#pragma unroll
    for (int i = 0; i < 4; ++i)
#pragma unroll
        for (int j = 0; j < 2; ++j) acc[i][j] = (floatx4){0.f, 0.f, 0.f, 0.f};

#pragma unroll 2
    for (int k0 = 0; k0 < K; k0 += 32) {
        half8 a0 = *(const half8*)(aR + k0);
        half8 a1 = *(const half8*)(aR + rs16 + k0);
        half8 a2 = *(const half8*)(aR + 2 * rs16 + k0);
        half8 a3 = *(const half8*)(aR + 3 * rs16 + k0);
        half8 b0 = *(const half8*)(bR + k0);
        half8 b1 = *(const half8*)(bR + rs16 + k0);

        acc[0][0] = __builtin_amdgcn_mfma_f32_16x16x32_f16(a0, b0, acc[0][0], 0, 0, 0);
        acc[1][0] = __builtin_amdgcn_mfma_f32_16x16x32_f16(a1, b0, acc[1][0], 0, 0, 0);
        acc[2][0] = __builtin_amdgcn_mfma_f32_16x16x32_f16(a2, b0, acc[2][0], 0, 0, 0);
        acc[3][0] = __builtin_amdgcn_mfma_f32_16x16x32_f16(a3, b0, acc[3][0], 0, 0, 0);
        acc[0][1] = __builtin_amdgcn_mfma_f32_16x16x32_f16(a0, b1, acc[0][1], 0, 0, 0);
        acc[1][1] = __builtin_amdgcn_mfma_f32_16x16x32_f16(a1, b1, acc[1][1], 0, 0, 0);
        acc[2][1] = __builtin_amdgcn_mfma_f32_16x16x32_f16(a2, b1, acc[2][1], 0, 0, 0);
        acc[3][1] = __builtin_amdgcn_mfma_f32_16x16x32_f16(a3, b1, acc[3][1], 0, 0, 0);
    }

    // epilogue: C/D layout col=lane&15, row=(lane>>4)*4+reg
    const int er = (lane >> 4) * 4;
#pragma unroll
    for (int nt = 0; nt < 2; ++nt) {
        const int col = bn0 + wn + nt * 16 + fm;
        const float bv = bias[col];
#pragma unroll
        for (int mt = 0; mt < 4; ++mt) {
            const int row0 = bm0 + wm + mt * 16 + er;
#pragma unroll
            for (int r = 0; r < 4; ++r) {
                float v = acc[mt][nt][r] + bv;
                v = fmaxf(v, 0.0f);
                C[(size_t)(row0 + r) * N + col] = (_Float16)v;
            }
        }
    }
}

// ---------------------------------------------------------------------------
// Kernel 2: energy via MFMA f16, LDS-free direct fragment loads.
// E[t][s] = sum_k Q[t,k]*K[s,k] over k=dh=64 (2 MFMA k-steps).
// Block = 256 thr = 2x2 waves over 64t x 128s; wave = 32t x 64s.
// p = sigmoid((E/8 + eb)/0.2) stored fp32.
// ---------------------------------------------------------------------------
__global__ __launch_bounds__(256) void energy_mfma_kernel(
    const _Float16* __restrict__ Q, const _Float16* __restrict__ Kp,
    const float* __restrict__ eb_ptr, float* __restrict__ P)
{
    const int tid = threadIdx.x;
    const int bh  = blockIdx.x;
    const int b   = bh >> 4;
    const int h   = bh & 15;
    const int t0  = blockIdx.y << 6;
    const int s0  = blockIdx.z << 7;

    const int lane = tid & 63;
    const int wid  = tid >> 6;
    const int wm   = (wid >> 1) * 32;    // t offset of wave
    const int wn   = (wid & 1) * 64;     // s offset of wave
    const int fm   = lane & 15;
    const int fk   = (lane >> 4) * 8;

    const _Float16* qR = Q  + (size_t)(b * TGT_ + t0 + wm + fm) * D_ + h * DH_ + fk;
    const _Float16* kR = Kp + (size_t)(b * SRC_ + s0 + wn + fm) * D_ + h * DH_ + fk;

    floatx4 acc[2][4];
#pragma unroll
    for (int i = 0; i < 2; ++i)
#pragma unroll
        for (int j = 0; j < 4; ++j) acc[i][j] = (floatx4){0.f, 0.f, 0.f, 0.f};

#pragma unroll
    for (int ks = 0; ks < 2; ++ks) {
        const int ko = ks * 32;
        half8 a0 = *(const half8*)(qR + ko);
        half8 a1 = *(const half8*)(qR + (size_t)16 * D_ + ko);
        half8 b0 = *(const half8*)(kR + ko);
        half8 b1 = *(const half8*)(kR + (size_t)16 * D_ + ko);
        half8 b2 = *(const half8*)(kR + (size_t)32 * D_ + ko);
        half8 b3 = *(const half8*)(kR + (size_t)48 * D_ + ko);
        acc[0][0] = __builtin_amdgcn_mfma_f32_16x16x32_f16(a0, b0, acc[0][0], 0, 0, 0);
        acc[0][1] = __builtin_amdgcn_mfma_f32_16x16x32_f16(a0, b1, acc[0][1], 0, 0, 0);
        acc[0][2] = __builtin_amdgcn_mfma_f32_16x16x32_f16(a0, b2, acc[0][2], 0, 0, 0);
        acc[0][3] = __builtin_amdgcn_mfma_f32_16x16x32_f16(a0, b3, acc[0][3], 0, 0, 0);
        acc[1][0] = __builtin_amdgcn_mfma_f32_16x16x32_f16(a1, b0, acc[1][0], 0, 0, 0);
        acc[1][1] = __builtin_amdgcn_mfma_f32_16x16x32_f16(a1, b1, acc[1][1], 0, 0, 0);
        acc[1][2] = __builtin_amdgcn_mfma_f32_16x16x32_f16(a1, b2, acc[1][2], 0, 0, 0);
        acc[1][3] = __builtin_amdgcn_mfma_f32_16x16x32_f16(a1, b3, acc[1][3], 0, 0, 0);
    }

    const float eb = eb_ptr[0];
    const int er = (lane >> 4) * 4;
#pragma unroll
    for (int mt = 0; mt < 2; ++mt) {
#pragma unroll
        for (int nt = 0; nt < 4; ++nt) {
            const int s = s0 + wn + nt * 16 + fm;
#pragma unroll
            for (int r = 0; r < 4; ++r) {
                const int t = t0 + wm + mt * 16 + er + r;
                float x = (acc[mt][nt][r] * 0.125f + eb) * 5.0f;
                float p = 1.0f / (1.0f + __expf(-x));
                P[((size_t)bh * TGT_ + t) * SRC_ + s] = p;
            }
        }
    }
}

// ---------------------------------------------------------------------------
// Kernel 3: monotonic alignment, DPP scan + DEPTH-8 register-ring prefetch.
//   c_i[n] = alpha_{i-1}[n] + (1-p_i[n-1])*c_i[n-1];  alpha_i = p_i * c_i
// One wave per bh, 8 n per lane. Row-i body consumes ring slot i&7 and
// immediately issues the load of row i+8 into that slot: 8 row-bodies of
// latency cover (vs 2 before) — P reads come from L3/HBM at ~500-900 cyc.
// ---------------------------------------------------------------------------
__global__ __launch_bounds__(64) void align_kernel(
    const float* __restrict__ P, float* __restrict__ Alpha)
{
    const int bh   = blockIdx.x;
    const int lane = threadIdx.x;
    const float* prow = P + (size_t)bh * TGT_ * SRC_;
    float* arow       = Alpha + (size_t)bh * TGT_ * SRC_;
    const int n0 = lane << 3;

    float bprev[8];
#pragma unroll
    for (int j = 0; j < 8; ++j) bprev[j] = 0.0f;
    if (lane == 0) bprev[0] = 1.0f;

    float4 bufA[8], bufB[8];
#pragma unroll
    for (int j = 0; j < 8; ++j) {
        const float* r = prow + (size_t)j * SRC_ + n0;
        bufA[j] = *(const float4*)r;
        bufB[j] = *(const float4*)(r + 4);
    }

    for (int g = 0; g < TGT_ / 8; ++g) {
#pragma unroll
        for (int jj = 0; jj < 8; ++jj) {
            const int i = g * 8 + jj;
            float4 ca = bufA[jj], cb = bufB[jj];
            if (g < TGT_ / 8 - 1) {          // prefetch row i+8 into slot jj
                const float* r = prow + (size_t)(i + 8) * SRC_ + n0;
                bufA[jj] = *(const float4*)r;
                bufB[jj] = *(const float4*)(r + 4);
            }
            float pl[8] = {ca.x, ca.y, ca.z, ca.w, cb.x, cb.y, cb.z, cb.w};

            // pm1 = previous lane's pl[7]
            float pm1 = dppf<0x111>(pl[7]);
            {
                float r15 = rdlane(pl[7], 15);
                float r31 = rdlane(pl[7], 31);
                float r47 = rdlane(pl[7], 47);
                pm1 = (lane == 16) ? r15 : pm1;
                pm1 = (lane == 32) ? r31 : pm1;
                pm1 = (lane == 48) ? r47 : pm1;
            }
            float a[8];
            a[0] = (lane == 0) ? 0.0f : (1.0f - pm1);
#pragma unroll
            for (int j = 1; j < 8; ++j) a[j] = 1.0f - pl[j - 1];

            // in-lane inclusive operator scan, seeded with bprev
            float Aj[8], Bj[8];
            float A = a[0], Bv = bprev[0];
            Aj[0] = A; Bj[0] = Bv;
#pragma unroll
            for (int j = 1; j < 8; ++j) {
                Bv = fmaf(a[j], Bv, bprev[j]);
                A  = a[j] * A;
                Aj[j] = A; Bj[j] = Bv;
            }

            // 16-lane-segment inclusive Kogge-Stone via DPP row_shr
            float As_ = A, Bs = Bv;
            {
                float Ash, Bsh;
                Ash = dppf<0x111>(As_); Bsh = dppf<0x111>(Bs);
                Ash = ((lane & 15) >= 1) ? Ash : 1.0f;
                Bs  = fmaf(As_, Bsh, Bs); As_ = As_ * Ash;
                Ash = dppf<0x112>(As_); Bsh = dppf<0x112>(Bs);
                Ash = ((lane & 15) >= 2) ? Ash : 1.0f;
                Bs  = fmaf(As_, Bsh, Bs); As_ = As_ * Ash;
                Ash = dppf<0x114>(As_); Bsh = dppf<0x114>(Bs);
                Ash = ((lane & 15) >= 4) ? Ash : 1.0f;
                Bs  = fmaf(As_, Bsh, Bs); As_ = As_ * Ash;
                Ash = dppf<0x118>(As_); Bsh = dppf<0x118>(Bs);
                Ash = ((lane & 15) >= 8) ? Ash : 1.0f;
                Bs  = fmaf(As_, Bsh, Bs); As_ = As_ * Ash;
            }

            // cross-segment prefix
            float PB;
            {
                float A15 = rdlane(As_, 15), B15 = rdlane(Bs, 15);
                float A31 = rdlane(As_, 31), B31 = rdlane(Bs, 31);
                float B47 = rdlane(Bs, 47);
                float PB1 = B15;
                float PB2 = fmaf(A31, PB1, B31);
                float PB3 = fmaf(rdlane(As_, 47), PB2, B47);
                (void)A15;
                const int seg = lane >> 4;
                PB = (seg == 0) ? 0.0f : ((seg == 1) ? PB1 : ((seg == 2) ? PB2 : PB3));
            }

            // exclusive-in-segment carry
            float EA = dppf<0x111>(As_);
            float EB = dppf<0x111>(Bs);
            EA = (lane & 15) ? EA : 1.0f;
            float cin = fmaf(EA, PB, EB);

            float an[8];
#pragma unroll
            for (int j = 0; j < 8; ++j) {
                float c = fmaf(Aj[j], cin, Bj[j]);
                an[j] = pl[j] * c;
                bprev[j] = an[j];
            }
            float4 o0 = {an[0], an[1], an[2], an[3]};
            float4 o1 = {an[4], an[5], an[6], an[7]};
            float* dst = arow + (size_t)i * SRC_ + n0;
            *(float4*)dst       = o0;
            *(float4*)(dst + 4) = o1;
        }
    }
}

// ---------------------------------------------------------------------------
extern "C" void kernel_launch(void* const* d_in, const int* in_sizes, int n_in,
                              void* d_out, int out_size, void* d_ws, size_t ws_size,
                              hipStream_t stream) {
    const float* seqs = (const float*)d_in[0];
    const float* keys = (const float*)d_in[1];
    const float* q_w  = (const float*)d_in[2];
    const float* q_b  = (const float*)d_in[3];
    const float* k_w  = (const float*)d_in[4];
    const float* k_b  = (const float*)d_in[5];
    const float* eb   = (const float*)d_in[6];

    float* out   = (float*)d_out;
    float* P     = out;
    float* Alpha = out + (size_t)B_ * H_ * TGT_ * SRC_;

    _Float16* Qh = (_Float16*)d_ws;
    _Float16* Kh = Qh + (size_t)B_ * TGT_ * D_;
    _Float16* seqs_h = (_Float16*)Alpha;
    _Float16* keys_h = seqs_h + (size_t)B_ * TGT_ * D_;
    _Float16* qw_h   = keys_h + (size_t)B_ * SRC_ * D_;
    _Float16* kw_h   = qw_h + (size_t)D_ * D_;

    cvt_kernel<<<dim3(8192), 256, 0, stream>>>(seqs, keys, q_w, k_w,
                                               seqs_h, keys_h, qw_h, kw_h);
    {
        dim3 grid(B_ * TGT_ / 128, D_ / 64);
        proj_mfma_kernel<<<grid, 256, 0, stream>>>(seqs_h, qw_h, q_b, Qh,
                                                   B_ * TGT_, D_, D_);
    }
    {
        dim3 grid(B_ * SRC_ / 128, D_ / 64);
        proj_mfma_kernel<<<grid, 256, 0, stream>>>(keys_h, kw_h, k_b, Kh,
                                                   B_ * SRC_, D_, D_);
    }
    {
        dim3 grid(B_ * H_, TGT_ / 64, SRC_ / 128);
        energy_mfma_kernel<<<grid, 256, 0, stream>>>(Qh, Kh, eb, P);
    }
    align_kernel<<<dim3(B_ * H_), 64, 0, stream>>>(P, Alpha);
}

// Round 5
// 234.394 us; speedup vs baseline: 1.9997x; 1.2021x over previous
//
#include <hip/hip_runtime.h>

#define B_   8
#define TGT_ 256
#define SRC_ 512
#define D_   1024
#define H_   16
#define DH_  64

typedef _Float16 half4 __attribute__((ext_vector_type(4)));
typedef _Float16 half8 __attribute__((ext_vector_type(8)));
typedef float    floatx4 __attribute__((ext_vector_type(4)));

// DPP move: bound_ctrl=1 -> out-of-range source lanes produce 0.0f
template <int CTRL>
__device__ __forceinline__ float dppf(float x) {
    return __int_as_float(__builtin_amdgcn_update_dpp(
        0, __float_as_int(x), CTRL, 0xF, 0xF, true));
}
__device__ __forceinline__ float rdlane(float x, int lane) {
    return __int_as_float(__builtin_amdgcn_readlane(__float_as_int(x), lane));
}

// ---------------------------------------------------------------------------
// Kernel 1: fused fp32->f16 cvt + BOTH projections.
//   C = f16(relu(A @ W^T + bias)), A = seqs (blocks 0-15) or keys (16-47).
// 128m x 64n tile, BK=32, 256 thr = 2x2 waves. fp32 inputs are loaded
// coalesced (128 B per 8 lanes), converted in-register, staged to LDS via
// ds_write_b64. Depth-1 register pipeline: global loads for k+1 issue
// before the MFMA of k, so their latency overlaps compute + next barrier.
// LDS 12 KB/block -> 768 blocks = 3/CU co-resident for cross-block overlap.
// ---------------------------------------------------------------------------
__global__ __launch_bounds__(256) void proj_fused_kernel(
    const float* __restrict__ seqs, const float* __restrict__ keys,
    const float* __restrict__ q_w,  const float* __restrict__ k_w,
    const float* __restrict__ q_b,  const float* __restrict__ k_b,
    _Float16* __restrict__ Qh, _Float16* __restrict__ Kh)
{
    __shared__ _Float16 As[128 * 32];   // 8 KB, [row][k], stride 32 halves
    __shared__ _Float16 Ws[64 * 32];    // 4 KB

    const int tid = threadIdx.x;
    const int bx  = blockIdx.x;
    const int K   = D_;
    const int N   = D_;

    const float* A; const float* W; const float* bias; _Float16* C;
    int bm0;
    if (bx < 16) { A = seqs; W = q_w; bias = q_b; C = Qh; bm0 = bx * 128; }
    else         { A = keys; W = k_w; bias = k_b; C = Kh; bm0 = (bx - 16) * 128; }
    const int bn0 = blockIdx.y * 64;

    // loader: fp32-unit = 4 floats = 16 B.  A: 1024 units (4/thr), W: 512 (2/thr)
    // unit u: row u>>3, k-offset (u&7)*4.  u = tid + 256*i  -> row += 32*i.
    const int lrow = tid >> 3;
    const int lkc  = (tid & 7) * 4;
    const float* aG = A + (size_t)(bm0 + lrow) * K + lkc;
    const float* wG = W + (size_t)(bn0 + lrow) * K + lkc;
    _Float16* aL = As + tid * 4;        // + i*1024 halves per unit step
    _Float16* wL = Ws + tid * 4;

    float4 ra[4], rw[2];
#define PROJ_LOAD(k0)                                                       \
    {                                                                       \
        ra[0] = *(const float4*)(aG + (k0));                                \
        ra[1] = *(const float4*)(aG + (size_t)32 * K + (k0));               \
        ra[2] = *(const float4*)(aG + (size_t)64 * K + (k0));               \
        ra[3] = *(const float4*)(aG + (size_t)96 * K + (k0));               \
        rw[0] = *(const float4*)(wG + (k0));                                \
        rw[1] = *(const float4*)(wG + (size_t)32 * K + (k0));               \
    }

    floatx4 acc[4][2];
#pragma unroll
    for (int i = 0; i < 4; ++i)
#pragma unroll
        for (int j = 0; j < 2; ++j) acc[i][j] = (floatx4){0.f, 0.f, 0.f, 0.f};

    const int lane = tid & 63;
    const int wid  = tid >> 6;
    const int wm   = (wid >> 1) * 64;
    const int wn   = (wid & 1) * 32;
    const int fm   = lane & 15;
    const int fk   = (lane >> 4) * 8;
    const _Float16* aF = As + (wm + fm) * 32 + fk;
    const _Float16* bF = Ws + (wn + fm) * 32 + fk;

    PROJ_LOAD(0);

    for (int k0 = 0; k0 < K; k0 += 32) {
        __syncthreads();                 // LDS free (prev iter's reads done)
#pragma unroll
        for (int i = 0; i < 4; ++i) {
            half4 h = { (_Float16)ra[i].x, (_Float16)ra[i].y,
                        (_Float16)ra[i].z, (_Float16)ra[i].w };
            *(half4*)(aL + i * 1024) = h;
        }
#pragma unroll
        for (int i = 0; i < 2; ++i) {
            half4 h = { (_Float16)rw[i].x, (_Float16)rw[i].y,
                        (_Float16)rw[i].z, (_Float16)rw[i].w };
            *(half4*)(wL + i * 1024) = h;
        }
        if (k0 + 32 < K) PROJ_LOAD(k0 + 32);   // overlap with MFMA below
        __syncthreads();

        half8 a0 = *(const half8*)(aF);
        half8 a1 = *(const half8*)(aF + 16 * 32);
        half8 a2 = *(const half8*)(aF + 32 * 32);
        half8 a3 = *(const half8*)(aF + 48 * 32);
        half8 b0 = *(const half8*)(bF);
        half8 b1 = *(const half8*)(bF + 16 * 32);

        acc[0][0] = __builtin_amdgcn_mfma_f32_16x16x32_f16(a0, b0, acc[0][0], 0, 0, 0);
        acc[1][0] = __builtin_amdgcn_mfma_f32_16x16x32_f16(a1, b0, acc[1][0], 0, 0, 0);
        acc[2][0] = __builtin_amdgcn_mfma_f32_16x16x32_f16(a2, b0, acc[2][0], 0, 0, 0);
        acc[3][0] = __builtin_amdgcn_mfma_f32_16x16x32_f16(a3, b0, acc[3][0], 0, 0, 0);
        acc[0][1] = __builtin_amdgcn_mfma_f32_16x16x32_f16(a0, b1, acc[0][1], 0, 0, 0);
        acc[1][1] = __builtin_amdgcn_mfma_f32_16x16x32_f16(a1, b1, acc[1][1], 0, 0, 0);
        acc[2][1] = __builtin_amdgcn_mfma_f32_16x16x32_f16(a2, b1, acc[2][1], 0, 0, 0);
        acc[3][1] = __builtin_amdgcn_mfma_f32_16x16x32_f16(a3, b1, acc[3][1], 0, 0, 0);
    }

    // epilogue: C/D layout col=lane&15, row=(lane>>4)*4+reg
    const int er = (lane >> 4) * 4;
#pragma unroll
    for (int nt = 0; nt < 2; ++nt) {
        const int col = bn0 + wn + nt * 16 + fm;
        const float bv = bias[col];
#pragma unroll
        for (int mt = 0; mt < 4; ++mt) {
            const int row0 = bm0 + wm + mt * 16 + er;
#pragma unroll
            for (int r = 0; r < 4; ++r) {
                float v = acc[mt][nt][r] + bv;
                v = fmaxf(v, 0.0f);
                C[(size_t)(row0 + r) * N + col] = (_Float16)v;
            }
        }
    }
#undef PROJ_LOAD
}

// ---------------------------------------------------------------------------
// Kernel 2: energy via MFMA f16 with LDS staging (validated round-3 form).
// E[t][s] = sum_k Q[t,k]*K[s,k], k=dh=64. 64t x 128s tile, 2x2 waves.
// p = sigmoid((E/8 + eb)/0.2) stored fp32.
// ---------------------------------------------------------------------------
__global__ __launch_bounds__(256) void energy_mfma_kernel(
    const _Float16* __restrict__ Q, const _Float16* __restrict__ K,
    const float* __restrict__ eb_ptr, float* __restrict__ P)
{
    __shared__ __align__(16) _Float16 Qt[2 * 64 * 32];    // 8 KB
    __shared__ __align__(16) _Float16 Kt[2 * 128 * 32];   // 16 KB

    const int tid = threadIdx.x;
    const int bh  = blockIdx.x;
    const int b   = bh >> 4;
    const int h   = bh & 15;
    const int t0  = blockIdx.y << 6;
    const int s0  = blockIdx.z << 7;

#pragma unroll
    for (int u = 0; u < 2; ++u) {
        const int unit = tid + u * 256;
        const int row = unit >> 3, hc = unit & 7;
        half8 v = *(const half8*)(Q + ((size_t)(b * TGT_ + t0 + row)) * D_ + h * DH_ + hc * 8);
        *(half8*)(Qt + (hc >> 2) * (64 * 32) + row * 32 + (hc & 3) * 8) = v;
    }
#pragma unroll
    for (int u = 0; u < 4; ++u) {
        const int unit = tid + u * 256;
        const int row = unit >> 3, hc = unit & 7;
        half8 v = *(const half8*)(K + ((size_t)(b * SRC_ + s0 + row)) * D_ + h * DH_ + hc * 8);
        *(half8*)(Kt + (hc >> 2) * (128 * 32) + row * 32 + (hc & 3) * 8) = v;
    }
    __syncthreads();

    const int lane = tid & 63;
    const int wid  = tid >> 6;
    const int wm   = (wid >> 1) * 32;
    const int wn   = (wid & 1) * 64;
    const int fm   = lane & 15;
    const int fk   = (lane >> 4) * 8;

    floatx4 acc[2][4];
#pragma unroll
    for (int i = 0; i < 2; ++i)
#pragma unroll
        for (int j = 0; j < 4; ++j) acc[i][j] = (floatx4){0.f, 0.f, 0.f, 0.f};

#pragma unroll
    for (int ks = 0; ks < 2; ++ks) {
        const _Float16* aB = Qt + ks * (64 * 32) + (wm + fm) * 32 + fk;
        const _Float16* bB = Kt + ks * (128 * 32) + (wn + fm) * 32 + fk;
        half8 a0 = *(const half8*)(aB);
        half8 a1 = *(const half8*)(aB + 16 * 32);
        half8 b0 = *(const half8*)(bB);
        half8 b1 = *(const half8*)(bB + 16 * 32);
        half8 b2 = *(const half8*)(bB + 32 * 32);
        half8 b3 = *(const half8*)(bB + 48 * 32);
        acc[0][0] = __builtin_amdgcn_mfma_f32_16x16x32_f16(a0, b0, acc[0][0], 0, 0, 0);
        acc[0][1] = __builtin_amdgcn_mfma_f32_16x16x32_f16(a0, b1, acc[0][1], 0, 0, 0);
        acc[0][2] = __builtin_amdgcn_mfma_f32_16x16x32_f16(a0, b2, acc[0][2], 0, 0, 0);
        acc[0][3] = __builtin_amdgcn_mfma_f32_16x16x32_f16(a0, b3, acc[0][3], 0, 0, 0);
        acc[1][0] = __builtin_amdgcn_mfma_f32_16x16x32_f16(a1, b0, acc[1][0], 0, 0, 0);
        acc[1][1] = __builtin_amdgcn_mfma_f32_16x16x32_f16(a1, b1, acc[1][1], 0, 0, 0);
        acc[1][2] = __builtin_amdgcn_mfma_f32_16x16x32_f16(a1, b2, acc[1][2], 0, 0, 0);
        acc[1][3] = __builtin_amdgcn_mfma_f32_16x16x32_f16(a1, b3, acc[1][3], 0, 0, 0);
    }

    const float eb = eb_ptr[0];
    const int er = (lane >> 4) * 4;
#pragma unroll
    for (int mt = 0; mt < 2; ++mt) {
#pragma unroll
        for (int nt = 0; nt < 4; ++nt) {
            const int s = s0 + wn + nt * 16 + fm;
#pragma unroll
            for (int r = 0; r < 4; ++r) {
                const int t = t0 + wm + mt * 16 + er + r;
                float x = (acc[mt][nt][r] * 0.125f + eb) * 5.0f;
                float p = 1.0f / (1.0f + __expf(-x));
                P[((size_t)bh * TGT_ + t) * SRC_ + s] = p;
            }
        }
    }
}

// ---------------------------------------------------------------------------
// Kernel 3: monotonic alignment, DPP scan + depth-8 register-ring prefetch
// (validated round 4: align < 77 us). One wave per bh, 8 n per lane.
// ---------------------------------------------------------------------------
__global__ __launch_bounds__(64) void align_kernel(
    const float* __restrict__ P, float* __restrict__ Alpha)
{
    const int bh   = blockIdx.x;
    const int lane = threadIdx.x;
    const float* prow = P + (size_t)bh * TGT_ * SRC_;
    float* arow       = Alpha + (size_t)bh * TGT_ * SRC_;
    const int n0 = lane << 3;

    float bprev[8];
#pragma unroll
    for (int j = 0; j < 8; ++j) bprev[j] = 0.0f;
    if (lane == 0) bprev[0] = 1.0f;

    float4 bufA[8], bufB[8];
#pragma unroll
    for (int j = 0; j < 8; ++j) {
        const float* r = prow + (size_t)j * SRC_ + n0;
        bufA[j] = *(const float4*)r;
        bufB[j] = *(const float4*)(r + 4);
    }

    for (int g = 0; g < TGT_ / 8; ++g) {
#pragma unroll
        for (int jj = 0; jj < 8; ++jj) {
            const int i = g * 8 + jj;
            float4 ca = bufA[jj], cb = bufB[jj];
            if (g < TGT_ / 8 - 1) {
                const float* r = prow + (size_t)(i + 8) * SRC_ + n0;
                bufA[jj] = *(const float4*)r;
                bufB[jj] = *(const float4*)(r + 4);
            }
            float pl[8] = {ca.x, ca.y, ca.z, ca.w, cb.x, cb.y, cb.z, cb.w};

            float pm1 = dppf<0x111>(pl[7]);
            {
                float r15 = rdlane(pl[7], 15);
                float r31 = rdlane(pl[7], 31);
                float r47 = rdlane(pl[7], 47);
                pm1 = (lane == 16) ? r15 : pm1;
                pm1 = (lane == 32) ? r31 : pm1;
                pm1 = (lane == 48) ? r47 : pm1;
            }
            float a[8];
            a[0] = (lane == 0) ? 0.0f : (1.0f - pm1);
#pragma unroll
            for (int j = 1; j < 8; ++j) a[j] = 1.0f - pl[j - 1];

            float Aj[8], Bj[8];
            float A = a[0], Bv = bprev[0];
            Aj[0] = A; Bj[0] = Bv;
#pragma unroll
            for (int j = 1; j < 8; ++j) {
                Bv = fmaf(a[j], Bv, bprev[j]);
                A  = a[j] * A;
                Aj[j] = A; Bj[j] = Bv;
            }

            float As_ = A, Bs = Bv;
            {
                float Ash, Bsh;
                Ash = dppf<0x111>(As_); Bsh = dppf<0x111>(Bs);
                Ash = ((lane & 15) >= 1) ? Ash : 1.0f;
                Bs  = fmaf(As_, Bsh, Bs); As_ = As_ * Ash;
                Ash = dppf<0x112>(As_); Bsh = dppf<0x112>(Bs);
                Ash = ((lane & 15) >= 2) ? Ash : 1.0f;
                Bs  = fmaf(As_, Bsh, Bs); As_ = As_ * Ash;
                Ash = dppf<0x114>(As_); Bsh = dppf<0x114>(Bs);
                Ash = ((lane & 15) >= 4) ? Ash : 1.0f;
                Bs  = fmaf(As_, Bsh, Bs); As_ = As_ * Ash;
                Ash = dppf<0x118>(As_); Bsh = dppf<0x118>(Bs);
                Ash = ((lane & 15) >= 8) ? Ash : 1.0f;
                Bs  = fmaf(As_, Bsh, Bs); As_ = As_ * Ash;
            }

            float PB;
            {
                float B15 = rdlane(Bs, 15);
                float A31 = rdlane(As_, 31), B31 = rdlane(Bs, 31);
                float B47 = rdlane(Bs, 47);
                float PB1 = B15;
                float PB2 = fmaf(A31, PB1, B31);
                float PB3 = fmaf(rdlane(As_, 47), PB2, B47);
                const int seg = lane >> 4;
                PB = (seg == 0) ? 0.0f : ((seg == 1) ? PB1 : ((seg == 2) ? PB2 : PB3));
            }

            float EA = dppf<0x111>(As_);
            float EB = dppf<0x111>(Bs);
            EA = (lane & 15) ? EA : 1.0f;
            float cin = fmaf(EA, PB, EB);

            float an[8];
#pragma unroll
            for (int j = 0; j < 8; ++j) {
                float c = fmaf(Aj[j], cin, Bj[j]);
                an[j] = pl[j] * c;
                bprev[j] = an[j];
            }
            float4 o0 = {an[0], an[1], an[2], an[3]};
            float4 o1 = {an[4], an[5], an[6], an[7]};
            float* dst = arow + (size_t)i * SRC_ + n0;
            *(float4*)dst       = o0;
            *(float4*)(dst + 4) = o1;
        }
    }
}

// ---------------------------------------------------------------------------
extern "C" void kernel_launch(void* const* d_in, const int* in_sizes, int n_in,
                              void* d_out, int out_size, void* d_ws, size_t ws_size,
                              hipStream_t stream) {
    const float* seqs = (const float*)d_in[0];
    const float* keys = (const float*)d_in[1];
    const float* q_w  = (const float*)d_in[2];
    const float* q_b  = (const float*)d_in[3];
    const float* k_w  = (const float*)d_in[4];
    const float* k_b  = (const float*)d_in[5];
    const float* eb   = (const float*)d_in[6];

    float* out   = (float*)d_out;
    float* P     = out;
    float* Alpha = out + (size_t)B_ * H_ * TGT_ * SRC_;

    _Float16* Qh = (_Float16*)d_ws;                  // 2048x1024 f16
    _Float16* Kh = Qh + (size_t)B_ * TGT_ * D_;      // 4096x1024 f16

    {   // fused cvt + both projections: 16 blocks.x for Q-rows, 32 for K-rows
        dim3 grid(48, D_ / 64);
        proj_fused_kernel<<<grid, 256, 0, stream>>>(seqs, keys, q_w, k_w,
                                                    q_b, k_b, Qh, Kh);
    }
    {
        dim3 grid(B_ * H_, TGT_ / 64, SRC_ / 128);
        energy_mfma_kernel<<<grid, 256, 0, stream>>>(Qh, Kh, eb, P);
    }
    align_kernel<<<dim3(B_ * H_), 64, 0, stream>>>(P, Alpha);
}

// Round 6
// 233.316 us; speedup vs baseline: 2.0089x; 1.0046x over previous
//
#include <hip/hip_runtime.h>

#define B_   8
#define TGT_ 256
#define SRC_ 512
#define D_   1024
#define H_   16
#define DH_  64

typedef _Float16 half4 __attribute__((ext_vector_type(4)));
typedef _Float16 half8 __attribute__((ext_vector_type(8)));
typedef float    floatx4 __attribute__((ext_vector_type(4)));

__device__ __forceinline__ void async_ld16(const void* g, void* l) {
    __builtin_amdgcn_global_load_lds(
        (const __attribute__((address_space(1))) void*)g,
        (__attribute__((address_space(3))) void*)l, 16, 0, 0);
}

// DPP move: bound_ctrl=1 -> out-of-range source lanes produce 0.0f
template <int CTRL>
__device__ __forceinline__ float dppf(float x) {
    return __int_as_float(__builtin_amdgcn_update_dpp(
        0, __float_as_int(x), CTRL, 0xF, 0xF, true));
}
__device__ __forceinline__ float rdlane(float x, int lane) {
    return __int_as_float(__builtin_amdgcn_readlane(__float_as_int(x), lane));
}

// ---------------------------------------------------------------------------
// Kernel 0: fp32 -> f16 conversion for seqs / keys / q_w / k_w (validated r2).
// ---------------------------------------------------------------------------
__global__ __launch_bounds__(256) void cvt_kernel(
    const float* __restrict__ s0, const float* __restrict__ s1,
    const float* __restrict__ s2, const float* __restrict__ s3,
    _Float16* __restrict__ d0, _Float16* __restrict__ d1,
    _Float16* __restrict__ d2, _Float16* __restrict__ d3)
{
    const int bid = blockIdx.x;
    const float* src; _Float16* dst; int base;
    if      (bid < 2048) { src = s0; dst = d0; base = bid;        }
    else if (bid < 6144) { src = s1; dst = d1; base = bid - 2048; }
    else if (bid < 7168) { src = s2; dst = d2; base = bid - 6144; }
    else                 { src = s3; dst = d3; base = bid - 7168; }
    const int idx = (base * 256 + threadIdx.x) * 4;
    float4 v = *(const float4*)(src + idx);
    half4 o = { (_Float16)v.x, (_Float16)v.y, (_Float16)v.z, (_Float16)v.w };
    *(half4*)(dst + idx) = o;
}

// ---------------------------------------------------------------------------
// Kernel 1: C = f16(relu(A @ W^T + bias)) via MFMA f16, f16 inputs.
// BM=128, BN=128, BK=32, 256 thr = 2x2 waves, wave = 64m x 64n (4x4 tiles).
// Staging via global_load_lds width=16 (m97 pattern). blocks 0-15: Q rows,
// 16-47: K rows. launch_bounds(256,2): VGPR cap 256 -> no spill (needs ~110).
// ---------------------------------------------------------------------------
__global__ __launch_bounds__(256, 2) void proj_mfma_kernel(
    const _Float16* __restrict__ seqs_h, const _Float16* __restrict__ keys_h,
    const _Float16* __restrict__ qw_h,   const _Float16* __restrict__ kw_h,
    const float* __restrict__ q_b,       const float* __restrict__ k_b,
    _Float16* __restrict__ Qh, _Float16* __restrict__ Kh)
{
    __shared__ __align__(16) _Float16 As[128 * 32];   // 8 KB
    __shared__ __align__(16) _Float16 Ws[128 * 32];   // 8 KB

    const int tid = threadIdx.x;
    const int bx  = blockIdx.x;
    const int K   = D_, N = D_;

    const _Float16* A; const _Float16* W; const float* bias; _Float16* C;
    int bm0;
    if (bx < 16) { A = seqs_h; W = qw_h; bias = q_b; C = Qh; bm0 = bx * 128; }
    else         { A = keys_h; W = kw_h; bias = k_b; C = Kh; bm0 = (bx - 16) * 128; }
    const int bn0 = blockIdx.y * 128;

    // chunk c (0..511): row c>>2, k-offset (c&3)*8 halves (16 B)
    const int c0 = tid, c1 = tid + 256;
    const _Float16* gA0 = A + (size_t)(bm0 + (c0 >> 2)) * K + (c0 & 3) * 8;
    const _Float16* gA1 = A + (size_t)(bm0 + (c1 >> 2)) * K + (c1 & 3) * 8;
    const _Float16* gW0 = W + (size_t)(bn0 + (c0 >> 2)) * K + (c0 & 3) * 8;
    const _Float16* gW1 = W + (size_t)(bn0 + (c1 >> 2)) * K + (c1 & 3) * 8;
    _Float16* lA0 = As + c0 * 8;
    _Float16* lA1 = As + c1 * 8;
    _Float16* lW0 = Ws + c0 * 8;
    _Float16* lW1 = Ws + c1 * 8;

    floatx4 acc[4][4];
#pragma unroll
    for (int i = 0; i < 4; ++i)
#pragma unroll
        for (int j = 0; j < 4; ++j) acc[i][j] = (floatx4){0.f, 0.f, 0.f, 0.f};

    const int lane = tid & 63;
    const int wid  = tid >> 6;
    const int wm   = (wid >> 1) * 64;
    const int wn   = (wid & 1) * 64;
    const int fm   = lane & 15;
    const int fk   = (lane >> 4) * 8;
    const _Float16* aF = As + (wm + fm) * 32 + fk;
    const _Float16* bF = Ws + (wn + fm) * 32 + fk;

    for (int k0 = 0; k0 < K; k0 += 32) {
        __syncthreads();                 // prev iter's ds_reads drained
        async_ld16(gA0 + k0, lA0);
        async_ld16(gA1 + k0, lA1);
        async_ld16(gW0 + k0, lW0);
        async_ld16(gW1 + k0, lW1);
        __syncthreads();                 // vmcnt(0) drain: LDS tiles ready

        half8 a[4], b[4];
#pragma unroll
        for (int i = 0; i < 4; ++i) {
            a[i] = *(const half8*)(aF + i * 16 * 32);
            b[i] = *(const half8*)(bF + i * 16 * 32);
        }
#pragma unroll
        for (int mt = 0; mt < 4; ++mt)
#pragma unroll
            for (int nt = 0; nt < 4; ++nt)
                acc[mt][nt] = __builtin_amdgcn_mfma_f32_16x16x32_f16(
                    a[mt], b[nt], acc[mt][nt], 0, 0, 0);
    }

    // epilogue: C/D layout col=lane&15, row=(lane>>4)*4+reg
    const int er = (lane >> 4) * 4;
#pragma unroll
    for (int nt = 0; nt < 4; ++nt) {
        const int col = bn0 + wn + nt * 16 + fm;
        const float bv = bias[col];
#pragma unroll
        for (int mt = 0; mt < 4; ++mt) {
            const int row0 = bm0 + wm + mt * 16 + er;
#pragma unroll
            for (int r = 0; r < 4; ++r) {
                float v = acc[mt][nt][r] + bv;
                v = fmaxf(v, 0.0f);
                C[(size_t)(row0 + r) * N + col] = (_Float16)v;
            }
        }
    }
}

// ---------------------------------------------------------------------------
// Kernel 2: energy via MFMA f16 (r5 staging) + LDS-transposed coalesced
// epilogue.  E[t][s] = sum_k Q[t,k]*K[s,k], k=64. 64t x 128s tile, 2x2 waves.
// p = sigmoid((E/8+eb)/0.2) -> LDS (stride 132 to break bank alias) ->
// wave-coalesced float4 global stores (512 B segments vs 4x64 B before).
// ---------------------------------------------------------------------------
__global__ __launch_bounds__(256, 4) void energy_mfma_kernel(
    const _Float16* __restrict__ Q, const _Float16* __restrict__ K,
    const float* __restrict__ eb_ptr, float* __restrict__ P)
{
    __shared__ __align__(16) unsigned char smem[64 * 132 * 4];  // 33792 B
    _Float16* Qt = (_Float16*)smem;            // [2][64][32]  (8 KB)
    _Float16* Kt = Qt + 2 * 64 * 32;           // [2][128][32] (16 KB)
    float*    pT = (float*)smem;               // epilogue reuse, stride 132

    const int tid = threadIdx.x;
    const int bh  = blockIdx.x;
    const int b   = bh >> 4;
    const int h   = bh & 15;
    const int t0  = blockIdx.y << 6;
    const int s0  = blockIdx.z << 7;

#pragma unroll
    for (int u = 0; u < 2; ++u) {
        const int unit = tid + u * 256;
        const int row = unit >> 3, hc = unit & 7;
        half8 v = *(const half8*)(Q + ((size_t)(b * TGT_ + t0 + row)) * D_ + h * DH_ + hc * 8);
        *(half8*)(Qt + (hc >> 2) * (64 * 32) + row * 32 + (hc & 3) * 8) = v;
    }
#pragma unroll
    for (int u = 0; u < 4; ++u) {
        const int unit = tid + u * 256;
        const int row = unit >> 3, hc = unit & 7;
        half8 v = *(const half8*)(K + ((size_t)(b * SRC_ + s0 + row)) * D_ + h * DH_ + hc * 8);
        *(half8*)(Kt + (hc >> 2) * (128 * 32) + row * 32 + (hc & 3) * 8) = v;
    }
    __syncthreads();

    const int lane = tid & 63;
    const int wid  = tid >> 6;
    const int wm   = (wid >> 1) * 32;
    const int wn   = (wid & 1) * 64;
    const int fm   = lane & 15;
    const int fk   = (lane >> 4) * 8;

    floatx4 acc[2][4];
#pragma unroll
    for (int i = 0; i < 2; ++i)
#pragma unroll
        for (int j = 0; j < 4; ++j) acc[i][j] = (floatx4){0.f, 0.f, 0.f, 0.f};

#pragma unroll
    for (int ks = 0; ks < 2; ++ks) {
        const _Float16* aB = Qt + ks * (64 * 32) + (wm + fm) * 32 + fk;
        const _Float16* bB = Kt + ks * (128 * 32) + (wn + fm) * 32 + fk;
        half8 a0 = *(const half8*)(aB);
        half8 a1 = *(const half8*)(aB + 16 * 32);
        half8 b0 = *(const half8*)(bB);
        half8 b1 = *(const half8*)(bB + 16 * 32);
        half8 b2 = *(const half8*)(bB + 32 * 32);
        half8 b3 = *(const half8*)(bB + 48 * 32);
        acc[0][0] = __builtin_amdgcn_mfma_f32_16x16x32_f16(a0, b0, acc[0][0], 0, 0, 0);
        acc[0][1] = __builtin_amdgcn_mfma_f32_16x16x32_f16(a0, b1, acc[0][1], 0, 0, 0);
        acc[0][2] = __builtin_amdgcn_mfma_f32_16x16x32_f16(a0, b2, acc[0][2], 0, 0, 0);
        acc[0][3] = __builtin_amdgcn_mfma_f32_16x16x32_f16(a0, b3, acc[0][3], 0, 0, 0);
        acc[1][0] = __builtin_amdgcn_mfma_f32_16x16x32_f16(a1, b0, acc[1][0], 0, 0, 0);
        acc[1][1] = __builtin_amdgcn_mfma_f32_16x16x32_f16(a1, b1, acc[1][1], 0, 0, 0);
        acc[1][2] = __builtin_amdgcn_mfma_f32_16x16x32_f16(a1, b2, acc[1][2], 0, 0, 0);
        acc[1][3] = __builtin_amdgcn_mfma_f32_16x16x32_f16(a1, b3, acc[1][3], 0, 0, 0);
    }

    __syncthreads();   // staging reads drained before LDS reuse

    const float eb = eb_ptr[0];
    const int er = (lane >> 4) * 4;
#pragma unroll
    for (int mt = 0; mt < 2; ++mt) {
#pragma unroll
        for (int nt = 0; nt < 4; ++nt) {
            const int s_b = wn + nt * 16 + fm;
#pragma unroll
            for (int r = 0; r < 4; ++r) {
                const int t_b = wm + mt * 16 + er + r;
                float x = (acc[mt][nt][r] * 0.125f + eb) * 5.0f;
                float p = 1.0f / (1.0f + __expf(-x));
                pT[t_b * 132 + s_b] = p;
            }
        }
    }
    __syncthreads();

    // coalesced write-out: 2048 float4 units, 8 per thread
#pragma unroll
    for (int u0 = 0; u0 < 8; ++u0) {
        const int u = tid + u0 * 256;
        const int row = u >> 5, c = u & 31;
        float4 v = *(const float4*)&pT[row * 132 + c * 4];
        *(float4*)&P[((size_t)bh * TGT_ + t0 + row) * SRC_ + s0 + c * 4] = v;
    }
}

// ---------------------------------------------------------------------------
// Kernel 3: monotonic alignment, DPP scan + depth-8 register ring.
// launch_bounds(64,1): VGPR budget 512 -> ring (64 VGPRs) + state stay in
// registers (round-3 build spilled at VGPR_Count=28 -> scratch-bound rows).
// ---------------------------------------------------------------------------
__global__ __launch_bounds__(64, 1) void align_kernel(
    const float* __restrict__ P, float* __restrict__ Alpha)
{
    const int bh   = blockIdx.x;
    const int lane = threadIdx.x;
    const float* prow = P + (size_t)bh * TGT_ * SRC_;
    float* arow       = Alpha + (size_t)bh * TGT_ * SRC_;
    const int n0 = lane << 3;

    float bprev[8];
#pragma unroll
    for (int j = 0; j < 8; ++j) bprev[j] = 0.0f;
    if (lane == 0) bprev[0] = 1.0f;

    float4 bufA[8], bufB[8];
#pragma unroll
    for (int j = 0; j < 8; ++j) {
        const float* r = prow + (size_t)j * SRC_ + n0;
        bufA[j] = *(const float4*)r;
        bufB[j] = *(const float4*)(r + 4);
    }

    for (int g = 0; g < TGT_ / 8; ++g) {
#pragma unroll
        for (int jj = 0; jj < 8; ++jj) {
            const int i = g * 8 + jj;
            float4 ca = bufA[jj], cb = bufB[jj];
            if (i + 8 < TGT_) {
                const float* r = prow + (size_t)(i + 8) * SRC_ + n0;
                bufA[jj] = *(const float4*)r;
                bufB[jj] = *(const float4*)(r + 4);
            }
            float pl[8] = {ca.x, ca.y, ca.z, ca.w, cb.x, cb.y, cb.z, cb.w};

            float pm1 = dppf<0x111>(pl[7]);
            {
                float r15 = rdlane(pl[7], 15);
                float r31 = rdlane(pl[7], 31);
                float r47 = rdlane(pl[7], 47);
                pm1 = (lane == 16) ? r15 : pm1;
                pm1 = (lane == 32) ? r31 : pm1;
                pm1 = (lane == 48) ? r47 : pm1;
            }
            float a[8];
            a[0] = (lane == 0) ? 0.0f : (1.0f - pm1);
#pragma unroll
            for (int j = 1; j < 8; ++j) a[j] = 1.0f - pl[j - 1];

            float Aj[8], Bj[8];
            float A = a[0], Bv = bprev[0];
            Aj[0] = A; Bj[0] = Bv;
#pragma unroll
            for (int j = 1; j < 8; ++j) {
                Bv = fmaf(a[j], Bv, bprev[j]);
                A  = a[j] * A;
                Aj[j] = A; Bj[j] = Bv;
            }

            float As_ = A, Bs = Bv;
            {
                float Ash, Bsh;
                Ash = dppf<0x111>(As_); Bsh = dppf<0x111>(Bs);
                Ash = ((lane & 15) >= 1) ? Ash : 1.0f;
                Bs  = fmaf(As_, Bsh, Bs); As_ = As_ * Ash;
                Ash = dppf<0x112>(As_); Bsh = dppf<0x112>(Bs);
                Ash = ((lane & 15) >= 2) ? Ash : 1.0f;
                Bs  = fmaf(As_, Bsh, Bs); As_ = As_ * Ash;
                Ash = dppf<0x114>(As_); Bsh = dppf<0x114>(Bs);
                Ash = ((lane & 15) >= 4) ? Ash : 1.0f;
                Bs  = fmaf(As_, Bsh, Bs); As_ = As_ * Ash;
                Ash = dppf<0x118>(As_); Bsh = dppf<0x118>(Bs);
                Ash = ((lane & 15) >= 8) ? Ash : 1.0f;
                Bs  = fmaf(As_, Bsh, Bs); As_ = As_ * Ash;
            }

            float PB;
            {
                float B15 = rdlane(Bs, 15);
                float A31 = rdlane(As_, 31), B31 = rdlane(Bs, 31);
                float B47 = rdlane(Bs, 47);
                float PB1 = B15;
                float PB2 = fmaf(A31, PB1, B31);
                float PB3 = fmaf(rdlane(As_, 47), PB2, B47);
                const int seg = lane >> 4;
                PB = (seg == 0) ? 0.0f : ((seg == 1) ? PB1 : ((seg == 2) ? PB2 : PB3));
            }

            float EA = dppf<0x111>(As_);
            float EB = dppf<0x111>(Bs);
            EA = (lane & 15) ? EA : 1.0f;
            float cin = fmaf(EA, PB, EB);

            float an[8];
#pragma unroll
            for (int j = 0; j < 8; ++j) {
                float c = fmaf(Aj[j], cin, Bj[j]);
                an[j] = pl[j] * c;
                bprev[j] = an[j];
            }
            float4 o0 = {an[0], an[1], an[2], an[3]};
            float4 o1 = {an[4], an[5], an[6], an[7]};
            float* dst = arow + (size_t)i * SRC_ + n0;
            *(float4*)dst       = o0;
            *(float4*)(dst + 4) = o1;
        }
    }
}

// ---------------------------------------------------------------------------
extern "C" void kernel_launch(void* const* d_in, const int* in_sizes, int n_in,
                              void* d_out, int out_size, void* d_ws, size_t ws_size,
                              hipStream_t stream) {
    const float* seqs = (const float*)d_in[0];
    const float* keys = (const float*)d_in[1];
    const float* q_w  = (const float*)d_in[2];
    const float* q_b  = (const float*)d_in[3];
    const float* k_w  = (const float*)d_in[4];
    const float* k_b  = (const float*)d_in[5];
    const float* eb   = (const float*)d_in[6];

    float* out   = (float*)d_out;
    float* P     = out;
    float* Alpha = out + (size_t)B_ * H_ * TGT_ * SRC_;

    _Float16* Qh     = (_Float16*)d_ws;                   // 2048x1024 f16
    _Float16* Kh     = Qh + (size_t)B_ * TGT_ * D_;       // 4096x1024 f16
    _Float16* seqs_h = Kh + (size_t)B_ * SRC_ * D_;       // 2M
    _Float16* keys_h = seqs_h + (size_t)B_ * TGT_ * D_;   // 4M
    _Float16* qw_h   = keys_h + (size_t)B_ * SRC_ * D_;   // 1M
    _Float16* kw_h   = qw_h + (size_t)D_ * D_;            // 1M

    cvt_kernel<<<dim3(8192), 256, 0, stream>>>(seqs, keys, q_w, k_w,
                                               seqs_h, keys_h, qw_h, kw_h);
    {
        dim3 grid(48, D_ / 128);   // bx 0-15: Q (2048 rows), 16-47: K (4096)
        proj_mfma_kernel<<<grid, 256, 0, stream>>>(seqs_h, keys_h, qw_h, kw_h,
                                                   q_b, k_b, Qh, Kh);
    }
    {
        dim3 grid(B_ * H_, TGT_ / 64, SRC_ / 128);
        energy_mfma_kernel<<<grid, 256, 0, stream>>>(Qh, Kh, eb, P);
    }
    align_kernel<<<dim3(B_ * H_), 64, 0, stream>>>(P, Alpha);
}